// Round 1
// baseline (1319.732 us; speedup 1.0000x reference)
//
#include <hip/hip_runtime.h>

#define N_NODES 100000
#define N_EDGES 1000000
#define D 128
#define H 4
#define Dh 32
#define R 64
#define NEG_SLOPE 0.2f

// ---- float<->ordered-uint encoding for atomicMax on floats ----
__device__ __forceinline__ unsigned enc_f(float f) {
    unsigned u = __float_as_uint(f);
    return (u & 0x80000000u) ? ~u : (u | 0x80000000u);
}
__device__ __forceinline__ float dec_f(unsigned k) {
    unsigned u = (k & 0x80000000u) ? (k & 0x7FFFFFFFu) : ~k;
    return __uint_as_float(u);
}
#define ENC_NEG_INF 0x007FFFFFu   // enc_f(-inf)

// ---- init: zero out-accumulator, z; set mkey to enc(-inf) ----
__global__ __launch_bounds__(256) void k_init(float* out, unsigned* mkey, float* z) {
    for (long i = blockIdx.x * 256L + threadIdx.x; i < (long)N_NODES * D; i += (long)gridDim.x * 256L) {
        out[i] = 0.0f;
        if (i < (long)N_NODES * H) { mkey[i] = ENC_NEG_INF; z[i] = 0.0f; }
    }
}

// ---- GEMM: h = x @ W  (W staged in LDS, 32-row x-tiles, 4x4 register blocking) ----
__global__ __launch_bounds__(256) void k_gemm(const float* __restrict__ x, const float* __restrict__ W,
                                              float* __restrict__ h) {
    __shared__ float Wl[128 * 128];   // 64 KB
    __shared__ float Xl[32 * 128];    // 16 KB
    for (int i = threadIdx.x; i < 128 * 128 / 4; i += 256)
        reinterpret_cast<float4*>(Wl)[i] = reinterpret_cast<const float4*>(W)[i];
    const int tc = threadIdx.x & 31;   // col group: cols tc*4..tc*4+3
    const int tr = threadIdx.x >> 5;   // row group: rows tr*4..tr*4+3

    int rowBase = blockIdx.x * 32;
    if (rowBase >= N_NODES) return;
    // load X tile (32x128)
    for (int i = threadIdx.x; i < 32 * 128 / 4; i += 256) {
        int idx = i * 4; int r = idx >> 7; int c = idx & 127;
        int gr = rowBase + r;
        float4 v = make_float4(0, 0, 0, 0);
        if (gr < N_NODES) v = *reinterpret_cast<const float4*>(x + (long)gr * D + c);
        reinterpret_cast<float4*>(Xl)[i] = v;
    }
    __syncthreads();
    float acc[4][4] = {};
    #pragma unroll 8
    for (int k4 = 0; k4 < 32; ++k4) {
        float4 xv[4], wv[4];
        #pragma unroll
        for (int j = 0; j < 4; ++j) xv[j] = *reinterpret_cast<const float4*>(Xl + (tr * 4 + j) * 128 + k4 * 4);
        #pragma unroll
        for (int kk = 0; kk < 4; ++kk) wv[kk] = *reinterpret_cast<const float4*>(Wl + (k4 * 4 + kk) * 128 + tc * 4);
        #pragma unroll
        for (int j = 0; j < 4; ++j) {
            acc[j][0] += xv[j].x * wv[0].x + xv[j].y * wv[1].x + xv[j].z * wv[2].x + xv[j].w * wv[3].x;
            acc[j][1] += xv[j].x * wv[0].y + xv[j].y * wv[1].y + xv[j].z * wv[2].y + xv[j].w * wv[3].y;
            acc[j][2] += xv[j].x * wv[0].z + xv[j].y * wv[1].z + xv[j].z * wv[2].z + xv[j].w * wv[3].z;
            acc[j][3] += xv[j].x * wv[0].w + xv[j].y * wv[1].w + xv[j].z * wv[2].w + xv[j].w * wv[3].w;
        }
    }
    #pragma unroll
    for (int j = 0; j < 4; ++j) {
        int gr = rowBase + tr * 4 + j;
        if (gr < N_NODES)
            *reinterpret_cast<float4*>(h + (long)gr * D + tc * 4) =
                make_float4(acc[j][0], acc[j][1], acc[j][2], acc[j][3]);
    }
}

// ---- per-node attention partials: a_src[n,h], a_dst[n,h] ----
__global__ __launch_bounds__(256) void k_nodeatt(const float* __restrict__ h,
                                                 const float* __restrict__ att_src,
                                                 const float* __restrict__ att_dst,
                                                 float* __restrict__ a_src, float* __restrict__ a_dst) {
    int i = blockIdx.x * 256 + threadIdx.x;
    if (i >= N_NODES * H) return;
    int n = i >> 2, hd = i & 3;
    const float* hp = h + (long)n * D + hd * Dh;
    const float* as = att_src + hd * Dh;
    const float* ad = att_dst + hd * Dh;
    float s1 = 0.f, s2 = 0.f;
    #pragma unroll
    for (int j = 0; j < 8; ++j) {
        float4 hv = *reinterpret_cast<const float4*>(hp + j * 4);
        float4 av = *reinterpret_cast<const float4*>(as + j * 4);
        float4 dv = *reinterpret_cast<const float4*>(ad + j * 4);
        s1 += hv.x * av.x + hv.y * av.y + hv.z * av.z + hv.w * av.w;
        s2 += hv.x * dv.x + hv.y * dv.y + hv.z * dv.z + hv.w * dv.w;
    }
    a_src[i] = s1; a_dst[i] = s2;
}

// ---- per-relation partial: a_rel[r,h] ----
__global__ __launch_bounds__(256) void k_relatt(const float* __restrict__ rel_emb,
                                                const float* __restrict__ att_rel,
                                                float* __restrict__ a_rel) {
    int i = threadIdx.x;   // R*H = 256
    int t = i >> 2, hd = i & 3;
    const float* rp = rel_emb + (long)t * D + hd * Dh;
    const float* ar = att_rel + hd * Dh;
    float s = 0.f;
    #pragma unroll
    for (int j = 0; j < 8; ++j) {
        float4 rv = *reinterpret_cast<const float4*>(rp + j * 4);
        float4 av = *reinterpret_cast<const float4*>(ar + j * 4);
        s += rv.x * av.x + rv.y * av.y + rv.z * av.z + rv.w * av.w;
    }
    a_rel[i] = s;
}

// ---- edge pass A: logits (stored in alphaBuf) + atomicMax segment max ----
__global__ __launch_bounds__(256) void k_edgeA(const int* __restrict__ ei, const int* __restrict__ et,
                                               const float* __restrict__ a_src, const float* __restrict__ a_dst,
                                               const float* __restrict__ a_rel,
                                               float* __restrict__ alphaBuf, unsigned* __restrict__ mkey) {
    int e = blockIdx.x * 256 + threadIdx.x;
    if (e >= N_EDGES) return;
    int src = ei[e], dst = ei[N_EDGES + e], t = et[e];
    float4 ls = *reinterpret_cast<const float4*>(a_src + (long)src * H);
    float4 ld = *reinterpret_cast<const float4*>(a_dst + (long)dst * H);
    float4 lr = *reinterpret_cast<const float4*>(a_rel + (long)t * H);
    float lg[4] = { ls.x + ld.x + lr.x, ls.y + ld.y + lr.y, ls.z + ld.z + lr.z, ls.w + ld.w + lr.w };
    #pragma unroll
    for (int hd = 0; hd < 4; ++hd) {
        lg[hd] = lg[hd] >= 0.f ? lg[hd] : NEG_SLOPE * lg[hd];
        atomicMax(mkey + (long)dst * H + hd, enc_f(lg[hd]));
    }
    *reinterpret_cast<float4*>(alphaBuf + (long)e * H) = make_float4(lg[0], lg[1], lg[2], lg[3]);
}

// ---- edge pass B: e = exp(logit - m[dst]) (in place) + atomicAdd z ----
__global__ __launch_bounds__(256) void k_edgeB(const int* __restrict__ ei,
                                               const unsigned* __restrict__ mkey,
                                               float* __restrict__ alphaBuf, float* __restrict__ z) {
    int e = blockIdx.x * 256 + threadIdx.x;
    if (e >= N_EDGES) return;
    int dst = ei[N_EDGES + e];
    float4 lg = *reinterpret_cast<const float4*>(alphaBuf + (long)e * H);
    uint4 mk = *reinterpret_cast<const uint4*>(mkey + (long)dst * H);
    float e0 = expf(lg.x - dec_f(mk.x));
    float e1 = expf(lg.y - dec_f(mk.y));
    float e2 = expf(lg.z - dec_f(mk.z));
    float e3 = expf(lg.w - dec_f(mk.w));
    *reinterpret_cast<float4*>(alphaBuf + (long)e * H) = make_float4(e0, e1, e2, e3);
    atomicAdd(z + (long)dst * H + 0, e0);
    atomicAdd(z + (long)dst * H + 1, e1);
    atomicAdd(z + (long)dst * H + 2, e2);
    atomicAdd(z + (long)dst * H + 3, e3);
}

// ---- scatter: alpha = e/z (finalized in alphaBuf) + out += (h[src]+r)*alpha ----
// one 64-lane wave per edge; each lane owns 2 consecutive channels
__global__ __launch_bounds__(256) void k_scatter(const int* __restrict__ ei, const int* __restrict__ et,
                                                 const float* __restrict__ h, const float* __restrict__ rel_emb,
                                                 const float* __restrict__ z,
                                                 float* __restrict__ alphaBuf, float* __restrict__ out) {
    int e = blockIdx.x * 4 + (threadIdx.x >> 6);
    int lane = threadIdx.x & 63;
    if (e >= N_EDGES) return;
    int src = ei[e], dst = ei[N_EDGES + e], t = et[e];
    int hd = lane >> 4;                       // head of this lane's 2 channels
    float ev = alphaBuf[(long)e * H + hd];
    float zv = z[(long)dst * H + hd];
    float al = ev / (zv + 1e-16f);
    float ev2 = 0.f, zv2 = 0.f;
    if (lane < 4) { ev2 = alphaBuf[(long)e * H + lane]; zv2 = z[(long)dst * H + lane]; }
    int c = lane * 2;
    float2 hv = *reinterpret_cast<const float2*>(h + (long)src * D + c);
    float2 rv = *reinterpret_cast<const float2*>(rel_emb + (long)t * D + c);
    if (lane < 4) alphaBuf[(long)e * H + lane] = ev2 / (zv2 + 1e-16f);
    atomicAdd(out + (long)dst * D + c,     (hv.x + rv.x) * al);
    atomicAdd(out + (long)dst * D + c + 1, (hv.y + rv.y) * al);
}

// ---- gelu (tanh approx, jax default) in place over out ----
__global__ __launch_bounds__(256) void k_gelu(float* __restrict__ out) {
    long i = blockIdx.x * 256L + threadIdx.x;
    if (i >= (long)N_NODES * D / 4) return;
    float4 v = *reinterpret_cast<float4*>(out + i * 4);
    float* p = &v.x;
    #pragma unroll
    for (int j = 0; j < 4; ++j) {
        float xx = p[j];
        p[j] = 0.5f * xx * (1.0f + tanhf(0.7978845608028654f * (xx + 0.044715f * xx * xx * xx)));
    }
    *reinterpret_cast<float4*>(out + i * 4) = v;
}

extern "C" void kernel_launch(void* const* d_in, const int* in_sizes, int n_in,
                              void* d_out, int out_size, void* d_ws, size_t ws_size,
                              hipStream_t stream) {
    const float* x        = (const float*)d_in[0];
    const float* W        = (const float*)d_in[1];
    const float* rel_emb  = (const float*)d_in[2];
    const float* att_src  = (const float*)d_in[3];
    const float* att_dst  = (const float*)d_in[4];
    const float* att_rel  = (const float*)d_in[5];
    const int*   ei       = (const int*)d_in[6];
    const int*   et       = (const int*)d_in[7];

    float* out      = (float*)d_out;                 // [N, D]
    float* alphaBuf = out + (long)N_NODES * D;       // [E, H] (logits -> e -> alpha)

    float*    h     = (float*)d_ws;                  // [N, D]
    float*    a_src = h + (long)N_NODES * D;         // [N, H]
    float*    a_dst = a_src + (long)N_NODES * H;     // [N, H]
    float*    a_rel = a_dst + (long)N_NODES * H;     // [R, H]
    unsigned* mkey  = (unsigned*)(a_rel + R * H);    // [N, H]
    float*    z     = (float*)(mkey + (long)N_NODES * H); // [N, H]

    k_init<<<2048, 256, 0, stream>>>(out, mkey, z);
    k_gemm<<<(N_NODES + 31) / 32, 256, 0, stream>>>(x, W, h);
    k_nodeatt<<<(N_NODES * H + 255) / 256, 256, 0, stream>>>(h, att_src, att_dst, a_src, a_dst);
    k_relatt<<<1, 256, 0, stream>>>(rel_emb, att_rel, a_rel);
    k_edgeA<<<(N_EDGES + 255) / 256, 256, 0, stream>>>(ei, et, a_src, a_dst, a_rel, alphaBuf, mkey);
    k_edgeB<<<(N_EDGES + 255) / 256, 256, 0, stream>>>(ei, mkey, alphaBuf, z);
    k_scatter<<<(N_EDGES + 3) / 4, 256, 0, stream>>>(ei, et, h, rel_emb, z, alphaBuf, out);
    k_gelu<<<((N_NODES * D / 4) + 255) / 256, 256, 0, stream>>>(out);
}

// Round 2
// 756.544 us; speedup vs baseline: 1.7444x; 1.7444x over previous
//
#include <hip/hip_runtime.h>

#define N_NODES 100000
#define N_EDGES 1000000
#define D 128
#define H 4
#define Dh 32
#define R 64
#define NEG_SLOPE 0.2f

// ---- float<->ordered-uint encoding for atomicMax on floats ----
__device__ __forceinline__ unsigned enc_f(float f) {
    unsigned u = __float_as_uint(f);
    return (u & 0x80000000u) ? ~u : (u | 0x80000000u);
}
__device__ __forceinline__ float dec_f(unsigned k) {
    unsigned u = (k & 0x80000000u) ? (k & 0x7FFFFFFFu) : ~k;
    return __uint_as_float(u);
}
#define ENC_NEG_INF 0x007FFFFFu   // enc_f(-inf)

// ---- init: mkey=enc(-inf), z=0, count(cursor)=0 ----
__global__ __launch_bounds__(256) void k_init(unsigned* mkey, float* z, int* cnt) {
    int i = blockIdx.x * 256 + threadIdx.x;
    if (i < N_NODES * H) { mkey[i] = ENC_NEG_INF; z[i] = 0.0f; }
    if (i < N_NODES) cnt[i] = 0;
}

// ---- GEMM: h = x @ W  (W staged in LDS, 32-row x-tiles, 4x4 register blocking) ----
__global__ __launch_bounds__(256) void k_gemm(const float* __restrict__ x, const float* __restrict__ W,
                                              float* __restrict__ h) {
    __shared__ float Wl[128 * 128];   // 64 KB
    __shared__ float Xl[32 * 128];    // 16 KB
    for (int i = threadIdx.x; i < 128 * 128 / 4; i += 256)
        reinterpret_cast<float4*>(Wl)[i] = reinterpret_cast<const float4*>(W)[i];
    const int tc = threadIdx.x & 31;
    const int tr = threadIdx.x >> 5;

    int rowBase = blockIdx.x * 32;
    if (rowBase >= N_NODES) return;
    for (int i = threadIdx.x; i < 32 * 128 / 4; i += 256) {
        int idx = i * 4; int r = idx >> 7; int c = idx & 127;
        int gr = rowBase + r;
        float4 v = make_float4(0, 0, 0, 0);
        if (gr < N_NODES) v = *reinterpret_cast<const float4*>(x + (long)gr * D + c);
        reinterpret_cast<float4*>(Xl)[i] = v;
    }
    __syncthreads();
    float acc[4][4] = {};
    #pragma unroll 8
    for (int k4 = 0; k4 < 32; ++k4) {
        float4 xv[4], wv[4];
        #pragma unroll
        for (int j = 0; j < 4; ++j) xv[j] = *reinterpret_cast<const float4*>(Xl + (tr * 4 + j) * 128 + k4 * 4);
        #pragma unroll
        for (int kk = 0; kk < 4; ++kk) wv[kk] = *reinterpret_cast<const float4*>(Wl + (k4 * 4 + kk) * 128 + tc * 4);
        #pragma unroll
        for (int j = 0; j < 4; ++j) {
            acc[j][0] += xv[j].x * wv[0].x + xv[j].y * wv[1].x + xv[j].z * wv[2].x + xv[j].w * wv[3].x;
            acc[j][1] += xv[j].x * wv[0].y + xv[j].y * wv[1].y + xv[j].z * wv[2].y + xv[j].w * wv[3].y;
            acc[j][2] += xv[j].x * wv[0].z + xv[j].y * wv[1].z + xv[j].z * wv[2].z + xv[j].w * wv[3].z;
            acc[j][3] += xv[j].x * wv[0].w + xv[j].y * wv[1].w + xv[j].z * wv[2].w + xv[j].w * wv[3].w;
        }
    }
    #pragma unroll
    for (int j = 0; j < 4; ++j) {
        int gr = rowBase + tr * 4 + j;
        if (gr < N_NODES)
            *reinterpret_cast<float4*>(h + (long)gr * D + tc * 4) =
                make_float4(acc[j][0], acc[j][1], acc[j][2], acc[j][3]);
    }
}

// ---- per-node attention partials: a_src[n,h], a_dst[n,h] ----
__global__ __launch_bounds__(256) void k_nodeatt(const float* __restrict__ h,
                                                 const float* __restrict__ att_src,
                                                 const float* __restrict__ att_dst,
                                                 float* __restrict__ a_src, float* __restrict__ a_dst) {
    int i = blockIdx.x * 256 + threadIdx.x;
    if (i >= N_NODES * H) return;
    int n = i >> 2, hd = i & 3;
    const float* hp = h + (long)n * D + hd * Dh;
    const float* as = att_src + hd * Dh;
    const float* ad = att_dst + hd * Dh;
    float s1 = 0.f, s2 = 0.f;
    #pragma unroll
    for (int j = 0; j < 8; ++j) {
        float4 hv = *reinterpret_cast<const float4*>(hp + j * 4);
        float4 av = *reinterpret_cast<const float4*>(as + j * 4);
        float4 dv = *reinterpret_cast<const float4*>(ad + j * 4);
        s1 += hv.x * av.x + hv.y * av.y + hv.z * av.z + hv.w * av.w;
        s2 += hv.x * dv.x + hv.y * dv.y + hv.z * dv.z + hv.w * dv.w;
    }
    a_src[i] = s1; a_dst[i] = s2;
}

// ---- per-relation partial: a_rel[r,h] ----
__global__ __launch_bounds__(256) void k_relatt(const float* __restrict__ rel_emb,
                                                const float* __restrict__ att_rel,
                                                float* __restrict__ a_rel) {
    int i = threadIdx.x;   // R*H = 256
    int t = i >> 2, hd = i & 3;
    const float* rp = rel_emb + (long)t * D + hd * Dh;
    const float* ar = att_rel + hd * Dh;
    float s = 0.f;
    #pragma unroll
    for (int j = 0; j < 8; ++j) {
        float4 rv = *reinterpret_cast<const float4*>(rp + j * 4);
        float4 av = *reinterpret_cast<const float4*>(ar + j * 4);
        s += rv.x * av.x + rv.y * av.y + rv.z * av.z + rv.w * av.w;
    }
    a_rel[i] = s;
}

// ---- edge pass A: logits (stored in alphaBuf) + atomicMax segment max + histogram ----
__global__ __launch_bounds__(256) void k_edgeA(const int* __restrict__ ei, const int* __restrict__ et,
                                               const float* __restrict__ a_src, const float* __restrict__ a_dst,
                                               const float* __restrict__ a_rel,
                                               float* __restrict__ alphaBuf, unsigned* __restrict__ mkey,
                                               int* __restrict__ cnt) {
    int e = blockIdx.x * 256 + threadIdx.x;
    if (e >= N_EDGES) return;
    int src = ei[e], dst = ei[N_EDGES + e], t = et[e];
    float4 ls = *reinterpret_cast<const float4*>(a_src + (long)src * H);
    float4 ld = *reinterpret_cast<const float4*>(a_dst + (long)dst * H);
    float4 lr = *reinterpret_cast<const float4*>(a_rel + (long)t * H);
    float lg[4] = { ls.x + ld.x + lr.x, ls.y + ld.y + lr.y, ls.z + ld.z + lr.z, ls.w + ld.w + lr.w };
    #pragma unroll
    for (int hd = 0; hd < 4; ++hd) {
        lg[hd] = lg[hd] >= 0.f ? lg[hd] : NEG_SLOPE * lg[hd];
        atomicMax(mkey + (long)dst * H + hd, enc_f(lg[hd]));
    }
    atomicAdd(cnt + dst, 1);
    *reinterpret_cast<float4*>(alphaBuf + (long)e * H) = make_float4(lg[0], lg[1], lg[2], lg[3]);
}

// ---- edge pass B: e = exp(logit - m[dst]) (in place) + atomicAdd z ----
__global__ __launch_bounds__(256) void k_edgeB(const int* __restrict__ ei,
                                               const unsigned* __restrict__ mkey,
                                               float* __restrict__ alphaBuf, float* __restrict__ z) {
    int e = blockIdx.x * 256 + threadIdx.x;
    if (e >= N_EDGES) return;
    int dst = ei[N_EDGES + e];
    float4 lg = *reinterpret_cast<const float4*>(alphaBuf + (long)e * H);
    uint4 mk = *reinterpret_cast<const uint4*>(mkey + (long)dst * H);
    float e0 = expf(lg.x - dec_f(mk.x));
    float e1 = expf(lg.y - dec_f(mk.y));
    float e2 = expf(lg.z - dec_f(mk.z));
    float e3 = expf(lg.w - dec_f(mk.w));
    *reinterpret_cast<float4*>(alphaBuf + (long)e * H) = make_float4(e0, e1, e2, e3);
    atomicAdd(z + (long)dst * H + 0, e0);
    atomicAdd(z + (long)dst * H + 1, e1);
    atomicAdd(z + (long)dst * H + 2, e2);
    atomicAdd(z + (long)dst * H + 3, e3);
}

// ---- scan stage 1: per-1024-chunk exclusive scan of cnt -> offs, chunk totals ----
__global__ __launch_bounds__(1024) void k_scan1(const int* __restrict__ cnt, int* __restrict__ offs,
                                                int* __restrict__ blksum) {
    __shared__ int s[1024];
    int tid = threadIdx.x;
    int i = blockIdx.x * 1024 + tid;
    int v = (i < N_NODES) ? cnt[i] : 0;
    s[tid] = v;
    __syncthreads();
    #pragma unroll
    for (int off = 1; off < 1024; off <<= 1) {
        int t = (tid >= off) ? s[tid - off] : 0;
        __syncthreads();
        s[tid] += t;
        __syncthreads();
    }
    if (i < N_NODES) offs[i] = s[tid] - v;   // exclusive
    if (tid == 1023) blksum[blockIdx.x] = s[1023];
}

// ---- scan stage 2: exclusive scan of chunk totals (single thread, ~98 elems) ----
__global__ void k_scan2(int* __restrict__ blksum, int nblk) {
    if (threadIdx.x == 0 && blockIdx.x == 0) {
        int run = 0;
        for (int b = 0; b < nblk; ++b) { int t = blksum[b]; blksum[b] = run; run += t; }
    }
}

// ---- scan stage 3: add chunk offsets; seed cursor; offs[N]=E ----
__global__ __launch_bounds__(256) void k_scan3(int* __restrict__ offs, const int* __restrict__ blksum,
                                               int* __restrict__ cursor) {
    int i = blockIdx.x * 256 + threadIdx.x;
    if (i < N_NODES) {
        int o = offs[i] + blksum[i >> 10];
        offs[i] = o;
        cursor[i] = o;
        if (i == 0) offs[N_NODES] = N_EDGES;
    }
}

// ---- fill CSR edge-id list ----
__global__ __launch_bounds__(256) void k_fill(const int* __restrict__ ei, int* __restrict__ cursor,
                                              int* __restrict__ eidx) {
    int e = blockIdx.x * 256 + threadIdx.x;
    if (e >= N_EDGES) return;
    int dst = ei[N_EDGES + e];
    int pos = atomicAdd(cursor + dst, 1);
    eidx[pos] = e;
}

// ---- gather: one wave per node. acc = sum (h[src]+rel[t])*alpha; alpha finalized; gelu; out ----
__global__ __launch_bounds__(256) void k_gather(const int* __restrict__ ei, const int* __restrict__ et,
                                                const int* __restrict__ offs, const int* __restrict__ eidx,
                                                const float* __restrict__ h, const float* __restrict__ rel_emb,
                                                const float* __restrict__ z,
                                                float* __restrict__ alphaBuf, float* __restrict__ out) {
    int n = blockIdx.x * 4 + (threadIdx.x >> 6);
    int lane = threadIdx.x & 63;
    if (n >= N_NODES) return;
    int start = offs[n], end = offs[n + 1];
    int hd = lane >> 4;                 // head owning channels c..c+1
    int c = lane * 2;
    float rzh = 1.0f / (z[(long)n * H + hd] + 1e-16f);
    float rz4 = (lane < H) ? 1.0f / (z[(long)n * H + lane] + 1e-16f) : 0.f;
    float accx = 0.f, accy = 0.f;

    for (int base = start; base < end; base += 64) {
        int cntc = end - base; if (cntc > 64) cntc = 64;
        int myEid = 0, mySrc = 0, myT = 0;
        if (lane < cntc) {
            myEid = eidx[base + lane];
            mySrc = ei[myEid];
            myT = et[myEid];
        }
        for (int j = 0; j < cntc; ++j) {
            int eid = __shfl(myEid, j);
            int src = __shfl(mySrc, j);
            int t   = __shfl(myT, j);
            float ev = alphaBuf[(long)eid * H + hd];     // broadcast per 16-lane group
            float evMine = __shfl(ev, lane << 4);        // head-'lane' value for lanes 0..3
            if (lane < H) alphaBuf[(long)eid * H + lane] = evMine * rz4;
            float al = ev * rzh;
            float2 hv = *reinterpret_cast<const float2*>(h + (long)src * D + c);
            float2 rv = *reinterpret_cast<const float2*>(rel_emb + (long)t * D + c);
            accx += (hv.x + rv.x) * al;
            accy += (hv.y + rv.y) * al;
        }
    }
    // gelu (tanh approx, jax default)
    float g0 = 0.5f * accx * (1.0f + tanhf(0.7978845608028654f * (accx + 0.044715f * accx * accx * accx)));
    float g1 = 0.5f * accy * (1.0f + tanhf(0.7978845608028654f * (accy + 0.044715f * accy * accy * accy)));
    *reinterpret_cast<float2*>(out + (long)n * D + c) = make_float2(g0, g1);
}

extern "C" void kernel_launch(void* const* d_in, const int* in_sizes, int n_in,
                              void* d_out, int out_size, void* d_ws, size_t ws_size,
                              hipStream_t stream) {
    const float* x        = (const float*)d_in[0];
    const float* W        = (const float*)d_in[1];
    const float* rel_emb  = (const float*)d_in[2];
    const float* att_src  = (const float*)d_in[3];
    const float* att_dst  = (const float*)d_in[4];
    const float* att_rel  = (const float*)d_in[5];
    const int*   ei       = (const int*)d_in[6];
    const int*   et       = (const int*)d_in[7];

    float* out      = (float*)d_out;                 // [N, D]
    float* alphaBuf = out + (long)N_NODES * D;       // [E, H] (logits -> e -> alpha)

    float*    h      = (float*)d_ws;                      // [N, D]
    float*    a_src  = h + (long)N_NODES * D;             // [N, H]
    float*    a_dst  = a_src + (long)N_NODES * H;         // [N, H]
    float*    a_rel  = a_dst + (long)N_NODES * H;         // [R, H]
    unsigned* mkey   = (unsigned*)(a_rel + R * H);        // [N, H]
    float*    z      = (float*)(mkey + (long)N_NODES * H);// [N, H]
    int*      cursor = (int*)(z + (long)N_NODES * H);     // [N]  (histogram, then fill cursor)
    int*      offs   = cursor + N_NODES;                  // [N+1]
    int*      blksum = offs + N_NODES + 1;                // [128]
    int*      eidx   = blksum + 128;                      // [E]

    const int NBLK = (N_NODES + 1023) / 1024;

    k_init<<<(N_NODES * H + 255) / 256, 256, 0, stream>>>(mkey, z, cursor);
    k_gemm<<<(N_NODES + 31) / 32, 256, 0, stream>>>(x, W, h);
    k_nodeatt<<<(N_NODES * H + 255) / 256, 256, 0, stream>>>(h, att_src, att_dst, a_src, a_dst);
    k_relatt<<<1, 256, 0, stream>>>(rel_emb, att_rel, a_rel);
    k_edgeA<<<(N_EDGES + 255) / 256, 256, 0, stream>>>(ei, et, a_src, a_dst, a_rel, alphaBuf, mkey, cursor);
    k_edgeB<<<(N_EDGES + 255) / 256, 256, 0, stream>>>(ei, mkey, alphaBuf, z);
    k_scan1<<<NBLK, 1024, 0, stream>>>(cursor, offs, blksum);
    k_scan2<<<1, 64, 0, stream>>>(blksum, NBLK);
    k_scan3<<<(N_NODES + 255) / 256, 256, 0, stream>>>(offs, blksum, cursor);
    k_fill<<<(N_EDGES + 255) / 256, 256, 0, stream>>>(ei, cursor, eidx);
    k_gather<<<(N_NODES + 3) / 4, 256, 0, stream>>>(ei, et, offs, eidx, h, rel_emb, z, alphaBuf, out);
}

// Round 3
// 434.931 us; speedup vs baseline: 3.0344x; 1.7395x over previous
//
#include <hip/hip_runtime.h>

#define N_NODES 100000
#define N_EDGES 1000000
#define D 128
#define H 4
#define Dh 32
#define R 64
#define NEG_SLOPE 0.2f
#define NEG_BIG -3.0e38f

// ---- init not needed beyond memset (cursor) ----

// ---- histogram of dst ----
__global__ __launch_bounds__(256) void k_hist(const int* __restrict__ ei, int* __restrict__ cnt) {
    int e = blockIdx.x * 256 + threadIdx.x;
    if (e >= N_EDGES) return;
    atomicAdd(cnt + ei[N_EDGES + e], 1);
}

// ---- GEMM: h = x @ W  (W staged in LDS, 32-row x-tiles, 4x4 register blocking) ----
__global__ __launch_bounds__(256) void k_gemm(const float* __restrict__ x, const float* __restrict__ W,
                                              float* __restrict__ h) {
    __shared__ float Wl[128 * 128];   // 64 KB
    __shared__ float Xl[32 * 128];    // 16 KB
    for (int i = threadIdx.x; i < 128 * 128 / 4; i += 256)
        reinterpret_cast<float4*>(Wl)[i] = reinterpret_cast<const float4*>(W)[i];
    const int tc = threadIdx.x & 31;
    const int tr = threadIdx.x >> 5;

    int rowBase = blockIdx.x * 32;
    if (rowBase >= N_NODES) return;
    for (int i = threadIdx.x; i < 32 * 128 / 4; i += 256) {
        int idx = i * 4; int r = idx >> 7; int c = idx & 127;
        int gr = rowBase + r;
        float4 v = make_float4(0, 0, 0, 0);
        if (gr < N_NODES) v = *reinterpret_cast<const float4*>(x + (long)gr * D + c);
        reinterpret_cast<float4*>(Xl)[i] = v;
    }
    __syncthreads();
    float acc[4][4] = {};
    #pragma unroll 8
    for (int k4 = 0; k4 < 32; ++k4) {
        float4 xv[4], wv[4];
        #pragma unroll
        for (int j = 0; j < 4; ++j) xv[j] = *reinterpret_cast<const float4*>(Xl + (tr * 4 + j) * 128 + k4 * 4);
        #pragma unroll
        for (int kk = 0; kk < 4; ++kk) wv[kk] = *reinterpret_cast<const float4*>(Wl + (k4 * 4 + kk) * 128 + tc * 4);
        #pragma unroll
        for (int j = 0; j < 4; ++j) {
            acc[j][0] += xv[j].x * wv[0].x + xv[j].y * wv[1].x + xv[j].z * wv[2].x + xv[j].w * wv[3].x;
            acc[j][1] += xv[j].x * wv[0].y + xv[j].y * wv[1].y + xv[j].z * wv[2].y + xv[j].w * wv[3].y;
            acc[j][2] += xv[j].x * wv[0].z + xv[j].y * wv[1].z + xv[j].z * wv[2].z + xv[j].w * wv[3].z;
            acc[j][3] += xv[j].x * wv[0].w + xv[j].y * wv[1].w + xv[j].z * wv[2].w + xv[j].w * wv[3].w;
        }
    }
    #pragma unroll
    for (int j = 0; j < 4; ++j) {
        int gr = rowBase + tr * 4 + j;
        if (gr < N_NODES)
            *reinterpret_cast<float4*>(h + (long)gr * D + tc * 4) =
                make_float4(acc[j][0], acc[j][1], acc[j][2], acc[j][3]);
    }
}

// ---- per-node attention partials: a_src[n,h], a_dst[n,h] ----
__global__ __launch_bounds__(256) void k_nodeatt(const float* __restrict__ h,
                                                 const float* __restrict__ att_src,
                                                 const float* __restrict__ att_dst,
                                                 float* __restrict__ a_src, float* __restrict__ a_dst) {
    int i = blockIdx.x * 256 + threadIdx.x;
    if (i >= N_NODES * H) return;
    int n = i >> 2, hd = i & 3;
    const float* hp = h + (long)n * D + hd * Dh;
    const float* as = att_src + hd * Dh;
    const float* ad = att_dst + hd * Dh;
    float s1 = 0.f, s2 = 0.f;
    #pragma unroll
    for (int j = 0; j < 8; ++j) {
        float4 hv = *reinterpret_cast<const float4*>(hp + j * 4);
        float4 av = *reinterpret_cast<const float4*>(as + j * 4);
        float4 dv = *reinterpret_cast<const float4*>(ad + j * 4);
        s1 += hv.x * av.x + hv.y * av.y + hv.z * av.z + hv.w * av.w;
        s2 += hv.x * dv.x + hv.y * dv.y + hv.z * dv.z + hv.w * dv.w;
    }
    a_src[i] = s1; a_dst[i] = s2;
}

// ---- per-relation partial: a_rel[r,h] ----
__global__ __launch_bounds__(256) void k_relatt(const float* __restrict__ rel_emb,
                                                const float* __restrict__ att_rel,
                                                float* __restrict__ a_rel) {
    int i = threadIdx.x;   // R*H = 256
    int t = i >> 2, hd = i & 3;
    const float* rp = rel_emb + (long)t * D + hd * Dh;
    const float* ar = att_rel + hd * Dh;
    float s = 0.f;
    #pragma unroll
    for (int j = 0; j < 8; ++j) {
        float4 rv = *reinterpret_cast<const float4*>(rp + j * 4);
        float4 av = *reinterpret_cast<const float4*>(ar + j * 4);
        s += rv.x * av.x + rv.y * av.y + rv.z * av.z + rv.w * av.w;
    }
    a_rel[i] = s;
}

// ---- edge pass: logits only (leaky-relu'd), stored in alphaBuf. NO atomics ----
__global__ __launch_bounds__(256) void k_edgeA(const int* __restrict__ ei, const int* __restrict__ et,
                                               const float* __restrict__ a_src, const float* __restrict__ a_dst,
                                               const float* __restrict__ a_rel,
                                               float* __restrict__ alphaBuf) {
    int e = blockIdx.x * 256 + threadIdx.x;
    if (e >= N_EDGES) return;
    int src = ei[e], dst = ei[N_EDGES + e], t = et[e];
    float4 ls = *reinterpret_cast<const float4*>(a_src + (long)src * H);
    float4 ld = *reinterpret_cast<const float4*>(a_dst + (long)dst * H);
    float4 lr = *reinterpret_cast<const float4*>(a_rel + (long)t * H);
    float lg[4] = { ls.x + ld.x + lr.x, ls.y + ld.y + lr.y, ls.z + ld.z + lr.z, ls.w + ld.w + lr.w };
    #pragma unroll
    for (int hd = 0; hd < 4; ++hd)
        lg[hd] = lg[hd] >= 0.f ? lg[hd] : NEG_SLOPE * lg[hd];
    *reinterpret_cast<float4*>(alphaBuf + (long)e * H) = make_float4(lg[0], lg[1], lg[2], lg[3]);
}

// ---- scan stage 1: per-1024-chunk exclusive scan of cnt -> offs, chunk totals ----
__global__ __launch_bounds__(1024) void k_scan1(const int* __restrict__ cnt, int* __restrict__ offs,
                                                int* __restrict__ blksum) {
    __shared__ int s[1024];
    int tid = threadIdx.x;
    int i = blockIdx.x * 1024 + tid;
    int v = (i < N_NODES) ? cnt[i] : 0;
    s[tid] = v;
    __syncthreads();
    #pragma unroll
    for (int off = 1; off < 1024; off <<= 1) {
        int t = (tid >= off) ? s[tid - off] : 0;
        __syncthreads();
        s[tid] += t;
        __syncthreads();
    }
    if (i < N_NODES) offs[i] = s[tid] - v;   // exclusive
    if (tid == 1023) blksum[blockIdx.x] = s[1023];
}

__global__ void k_scan2(int* __restrict__ blksum, int nblk) {
    if (threadIdx.x == 0 && blockIdx.x == 0) {
        int run = 0;
        for (int b = 0; b < nblk; ++b) { int t = blksum[b]; blksum[b] = run; run += t; }
    }
}

__global__ __launch_bounds__(256) void k_scan3(int* __restrict__ offs, const int* __restrict__ blksum,
                                               int* __restrict__ cursor) {
    int i = blockIdx.x * 256 + threadIdx.x;
    if (i < N_NODES) {
        int o = offs[i] + blksum[i >> 10];
        offs[i] = o;
        cursor[i] = o;
        if (i == 0) offs[N_NODES] = N_EDGES;
    }
}

// ---- fill CSR edge-id list ----
__global__ __launch_bounds__(256) void k_fill(const int* __restrict__ ei, int* __restrict__ cursor,
                                              int* __restrict__ eidx) {
    int e = blockIdx.x * 256 + threadIdx.x;
    if (e >= N_EDGES) return;
    int dst = ei[N_EDGES + e];
    int pos = atomicAdd(cursor + dst, 1);
    eidx[pos] = e;
}

__device__ __forceinline__ float4 max4(float4 a, float4 b) {
    return make_float4(fmaxf(a.x, b.x), fmaxf(a.y, b.y), fmaxf(a.z, b.z), fmaxf(a.w, b.w));
}
__device__ __forceinline__ float4 add4(float4 a, float4 b) {
    return make_float4(a.x + b.x, a.y + b.y, a.z + b.z, a.w + b.w);
}
__device__ __forceinline__ float pick4(float4 v, int i) {
    float r = v.x;
    r = (i == 1) ? v.y : r;
    r = (i == 2) ? v.z : r;
    r = (i == 3) ? v.w : r;
    return r;
}

// ---- gather: one wave per node. softmax stats via butterfly, then
//      acc = sum (h[src]+rel[t])*alpha; alpha finalized; gelu; out ----
__global__ __launch_bounds__(256) void k_gather(const int* __restrict__ ei, const int* __restrict__ et,
                                                const int* __restrict__ offs, const int* __restrict__ eidx,
                                                const float* __restrict__ h, const float* __restrict__ rel_emb,
                                                float* __restrict__ alphaBuf, float* __restrict__ out) {
    int n = blockIdx.x * 4 + (threadIdx.x >> 6);
    int lane = threadIdx.x & 63;
    if (n >= N_NODES) return;
    int start = offs[n], end = offs[n + 1];
    int hd = lane >> 4;                 // head owning channels c..c+1
    int c = lane * 2;

    // ---- pass 1: per-head max and exp-sum over this node's edges ----
    float4 mylg = make_float4(NEG_BIG, NEG_BIG, NEG_BIG, NEG_BIG);
    int deg = end - start;
    bool have = lane < deg;
    if (have) {
        int eid = eidx[start + lane];
        mylg = *reinterpret_cast<const float4*>(alphaBuf + (long)eid * H);
    }
    float4 m4 = mylg;
    for (int base = start + 64; base < end; base += 64) {
        if (base + lane < end) {
            int eid = eidx[base + lane];
            float4 lg = *reinterpret_cast<const float4*>(alphaBuf + (long)eid * H);
            m4 = max4(m4, lg);
        }
    }
    #pragma unroll
    for (int off = 32; off >= 1; off >>= 1) {
        float4 o = make_float4(__shfl_xor(m4.x, off), __shfl_xor(m4.y, off),
                               __shfl_xor(m4.z, off), __shfl_xor(m4.w, off));
        m4 = max4(m4, o);
    }
    float4 z4 = make_float4(0, 0, 0, 0);
    if (have)
        z4 = make_float4(expf(mylg.x - m4.x), expf(mylg.y - m4.y),
                         expf(mylg.z - m4.z), expf(mylg.w - m4.w));
    for (int base = start + 64; base < end; base += 64) {
        if (base + lane < end) {
            int eid = eidx[base + lane];
            float4 lg = *reinterpret_cast<const float4*>(alphaBuf + (long)eid * H);
            z4 = add4(z4, make_float4(expf(lg.x - m4.x), expf(lg.y - m4.y),
                                      expf(lg.z - m4.z), expf(lg.w - m4.w)));
        }
    }
    #pragma unroll
    for (int off = 32; off >= 1; off >>= 1) {
        float4 o = make_float4(__shfl_xor(z4.x, off), __shfl_xor(z4.y, off),
                               __shfl_xor(z4.z, off), __shfl_xor(z4.w, off));
        z4 = add4(z4, o);
    }
    float mh  = pick4(m4, hd);
    float rzh = 1.0f / (pick4(z4, hd) + 1e-16f);
    float rz4 = (lane < H) ? 1.0f / (pick4(z4, lane) + 1e-16f) : 0.f;
    float mz4 = (lane < H) ? pick4(m4, lane) : 0.f;

    // ---- pass 2: message accumulation + alpha finalization ----
    float accx = 0.f, accy = 0.f;
    for (int base = start; base < end; base += 64) {
        int cntc = end - base; if (cntc > 64) cntc = 64;
        int myEid = 0, mySrc = 0, myT = 0;
        if (lane < cntc) {
            myEid = eidx[base + lane];
            mySrc = ei[myEid];
            myT = et[myEid];
        }
        for (int j = 0; j < cntc; ++j) {
            int eid = __shfl(myEid, j);
            int src = __shfl(mySrc, j);
            int t   = __shfl(myT, j);
            float lgv = alphaBuf[(long)eid * H + hd];    // broadcast per 16-lane group
            float ev = expf(lgv - mh);
            if (lane < H) {
                float lgm = alphaBuf[(long)eid * H + lane];
                alphaBuf[(long)eid * H + lane] = expf(lgm - mz4) * rz4;
            }
            float al = ev * rzh;
            float2 hv = *reinterpret_cast<const float2*>(h + (long)src * D + c);
            float2 rv = *reinterpret_cast<const float2*>(rel_emb + (long)t * D + c);
            accx += (hv.x + rv.x) * al;
            accy += (hv.y + rv.y) * al;
        }
    }
    // gelu (tanh approx, jax default)
    float g0 = 0.5f * accx * (1.0f + tanhf(0.7978845608028654f * (accx + 0.044715f * accx * accx * accx)));
    float g1 = 0.5f * accy * (1.0f + tanhf(0.7978845608028654f * (accy + 0.044715f * accy * accy * accy)));
    *reinterpret_cast<float2*>(out + (long)n * D + c) = make_float2(g0, g1);
}

extern "C" void kernel_launch(void* const* d_in, const int* in_sizes, int n_in,
                              void* d_out, int out_size, void* d_ws, size_t ws_size,
                              hipStream_t stream) {
    const float* x        = (const float*)d_in[0];
    const float* W        = (const float*)d_in[1];
    const float* rel_emb  = (const float*)d_in[2];
    const float* att_src  = (const float*)d_in[3];
    const float* att_dst  = (const float*)d_in[4];
    const float* att_rel  = (const float*)d_in[5];
    const int*   ei       = (const int*)d_in[6];
    const int*   et       = (const int*)d_in[7];

    float* out      = (float*)d_out;                 // [N, D]
    float* alphaBuf = out + (long)N_NODES * D;       // [E, H] (logits -> alpha)

    float*    h      = (float*)d_ws;                      // [N, D]
    float*    a_src  = h + (long)N_NODES * D;             // [N, H]
    float*    a_dst  = a_src + (long)N_NODES * H;         // [N, H]
    float*    a_rel  = a_dst + (long)N_NODES * H;         // [R, H]
    int*      cursor = (int*)(a_rel + R * H);             // [N]  (histogram, then fill cursor)
    int*      offs   = cursor + N_NODES;                  // [N+1]
    int*      blksum = offs + N_NODES + 1;                // [128]
    int*      eidx   = blksum + 128;                      // [E]

    const int NBLK = (N_NODES + 1023) / 1024;

    hipMemsetAsync(cursor, 0, N_NODES * sizeof(int), stream);
    k_hist<<<(N_EDGES + 255) / 256, 256, 0, stream>>>(ei, cursor);
    k_gemm<<<(N_NODES + 31) / 32, 256, 0, stream>>>(x, W, h);
    k_nodeatt<<<(N_NODES * H + 255) / 256, 256, 0, stream>>>(h, att_src, att_dst, a_src, a_dst);
    k_relatt<<<1, 256, 0, stream>>>(rel_emb, att_rel, a_rel);
    k_edgeA<<<(N_EDGES + 255) / 256, 256, 0, stream>>>(ei, et, a_src, a_dst, a_rel, alphaBuf);
    k_scan1<<<NBLK, 1024, 0, stream>>>(cursor, offs, blksum);
    k_scan2<<<1, 64, 0, stream>>>(blksum, NBLK);
    k_scan3<<<(N_NODES + 255) / 256, 256, 0, stream>>>(offs, blksum, cursor);
    k_fill<<<(N_EDGES + 255) / 256, 256, 0, stream>>>(ei, cursor, eidx);
    k_gather<<<(N_NODES + 3) / 4, 256, 0, stream>>>(ei, et, offs, eidx, h, rel_emb, alphaBuf, out);
}

// Round 4
// 389.866 us; speedup vs baseline: 3.3851x; 1.1156x over previous
//
#include <hip/hip_runtime.h>

#define N_NODES 100000
#define N_EDGES 1000000
#define D 128
#define H 4
#define Dh 32
#define R 64
#define NEG_SLOPE 0.2f
#define NEG_BIG -3.0e38f

// ---- histogram of dst ----
__global__ __launch_bounds__(256) void k_hist(const int* __restrict__ ei, int* __restrict__ cnt) {
    int e = blockIdx.x * 256 + threadIdx.x;
    if (e >= N_EDGES) return;
    atomicAdd(cnt + ei[N_EDGES + e], 1);
}

// ---- GEMM: h = x @ W  (W staged in LDS, 32-row x-tiles, 4x4 register blocking) ----
__global__ __launch_bounds__(256) void k_gemm(const float* __restrict__ x, const float* __restrict__ W,
                                              float* __restrict__ h) {
    __shared__ float Wl[128 * 128];   // 64 KB
    __shared__ float Xl[32 * 128];    // 16 KB
    for (int i = threadIdx.x; i < 128 * 128 / 4; i += 256)
        reinterpret_cast<float4*>(Wl)[i] = reinterpret_cast<const float4*>(W)[i];
    const int tc = threadIdx.x & 31;
    const int tr = threadIdx.x >> 5;

    int rowBase = blockIdx.x * 32;
    if (rowBase >= N_NODES) return;
    for (int i = threadIdx.x; i < 32 * 128 / 4; i += 256) {
        int idx = i * 4; int r = idx >> 7; int c = idx & 127;
        int gr = rowBase + r;
        float4 v = make_float4(0, 0, 0, 0);
        if (gr < N_NODES) v = *reinterpret_cast<const float4*>(x + (long)gr * D + c);
        reinterpret_cast<float4*>(Xl)[i] = v;
    }
    __syncthreads();
    float acc[4][4] = {};
    #pragma unroll 8
    for (int k4 = 0; k4 < 32; ++k4) {
        float4 xv[4], wv[4];
        #pragma unroll
        for (int j = 0; j < 4; ++j) xv[j] = *reinterpret_cast<const float4*>(Xl + (tr * 4 + j) * 128 + k4 * 4);
        #pragma unroll
        for (int kk = 0; kk < 4; ++kk) wv[kk] = *reinterpret_cast<const float4*>(Wl + (k4 * 4 + kk) * 128 + tc * 4);
        #pragma unroll
        for (int j = 0; j < 4; ++j) {
            acc[j][0] += xv[j].x * wv[0].x + xv[j].y * wv[1].x + xv[j].z * wv[2].x + xv[j].w * wv[3].x;
            acc[j][1] += xv[j].x * wv[0].y + xv[j].y * wv[1].y + xv[j].z * wv[2].y + xv[j].w * wv[3].y;
            acc[j][2] += xv[j].x * wv[0].z + xv[j].y * wv[1].z + xv[j].z * wv[2].z + xv[j].w * wv[3].z;
            acc[j][3] += xv[j].x * wv[0].w + xv[j].y * wv[1].w + xv[j].z * wv[2].w + xv[j].w * wv[3].w;
        }
    }
    #pragma unroll
    for (int j = 0; j < 4; ++j) {
        int gr = rowBase + tr * 4 + j;
        if (gr < N_NODES)
            *reinterpret_cast<float4*>(h + (long)gr * D + tc * 4) =
                make_float4(acc[j][0], acc[j][1], acc[j][2], acc[j][3]);
    }
}

// ---- per-node attention partials: a_src[n,h], a_dst[n,h] ----
__global__ __launch_bounds__(256) void k_nodeatt(const float* __restrict__ h,
                                                 const float* __restrict__ att_src,
                                                 const float* __restrict__ att_dst,
                                                 float* __restrict__ a_src, float* __restrict__ a_dst) {
    int i = blockIdx.x * 256 + threadIdx.x;
    if (i >= N_NODES * H) return;
    int n = i >> 2, hd = i & 3;
    const float* hp = h + (long)n * D + hd * Dh;
    const float* as = att_src + hd * Dh;
    const float* ad = att_dst + hd * Dh;
    float s1 = 0.f, s2 = 0.f;
    #pragma unroll
    for (int j = 0; j < 8; ++j) {
        float4 hv = *reinterpret_cast<const float4*>(hp + j * 4);
        float4 av = *reinterpret_cast<const float4*>(as + j * 4);
        float4 dv = *reinterpret_cast<const float4*>(ad + j * 4);
        s1 += hv.x * av.x + hv.y * av.y + hv.z * av.z + hv.w * av.w;
        s2 += hv.x * dv.x + hv.y * dv.y + hv.z * dv.z + hv.w * dv.w;
    }
    a_src[i] = s1; a_dst[i] = s2;
}

// ---- per-relation partial: a_rel[r,h] ----
__global__ __launch_bounds__(256) void k_relatt(const float* __restrict__ rel_emb,
                                                const float* __restrict__ att_rel,
                                                float* __restrict__ a_rel) {
    int i = threadIdx.x;   // R*H = 256
    int t = i >> 2, hd = i & 3;
    const float* rp = rel_emb + (long)t * D + hd * Dh;
    const float* ar = att_rel + hd * Dh;
    float s = 0.f;
    #pragma unroll
    for (int j = 0; j < 8; ++j) {
        float4 rv = *reinterpret_cast<const float4*>(rp + j * 4);
        float4 av = *reinterpret_cast<const float4*>(ar + j * 4);
        s += rv.x * av.x + rv.y * av.y + rv.z * av.z + rv.w * av.w;
    }
    a_rel[i] = s;
}

// ---- scan stage 1: per-1024-chunk exclusive scan of cnt -> offs, chunk totals ----
__global__ __launch_bounds__(1024) void k_scan1(const int* __restrict__ cnt, int* __restrict__ offs,
                                                int* __restrict__ blksum) {
    __shared__ int s[1024];
    int tid = threadIdx.x;
    int i = blockIdx.x * 1024 + tid;
    int v = (i < N_NODES) ? cnt[i] : 0;
    s[tid] = v;
    __syncthreads();
    #pragma unroll
    for (int off = 1; off < 1024; off <<= 1) {
        int t = (tid >= off) ? s[tid - off] : 0;
        __syncthreads();
        s[tid] += t;
        __syncthreads();
    }
    if (i < N_NODES) offs[i] = s[tid] - v;   // exclusive
    if (tid == 1023) blksum[blockIdx.x] = s[1023];
}

__global__ void k_scan2(int* __restrict__ blksum, int nblk) {
    if (threadIdx.x == 0 && blockIdx.x == 0) {
        int run = 0;
        for (int b = 0; b < nblk; ++b) { int t = blksum[b]; blksum[b] = run; run += t; }
    }
}

__global__ __launch_bounds__(256) void k_scan3(int* __restrict__ offs, const int* __restrict__ blksum,
                                               int* __restrict__ cursor) {
    int i = blockIdx.x * 256 + threadIdx.x;
    if (i < N_NODES) {
        int o = offs[i] + blksum[i >> 10];
        offs[i] = o;
        cursor[i] = o;
        if (i == 0) offs[N_NODES] = N_EDGES;
    }
}

// ---- fill CSR edge-id list ----
__global__ __launch_bounds__(256) void k_fill(const int* __restrict__ ei, int* __restrict__ cursor,
                                              int* __restrict__ eidx) {
    int e = blockIdx.x * 256 + threadIdx.x;
    if (e >= N_EDGES) return;
    int dst = ei[N_EDGES + e];
    int pos = atomicAdd(cursor + dst, 1);
    eidx[pos] = e;
}

__device__ __forceinline__ float4 max4(float4 a, float4 b) {
    return make_float4(fmaxf(a.x, b.x), fmaxf(a.y, b.y), fmaxf(a.z, b.z), fmaxf(a.w, b.w));
}
__device__ __forceinline__ float4 add4(float4 a, float4 b) {
    return make_float4(a.x + b.x, a.y + b.y, a.z + b.z, a.w + b.w);
}
__device__ __forceinline__ float4 lrelu4(float4 v) {
    return make_float4(v.x >= 0.f ? v.x : NEG_SLOPE * v.x,
                       v.y >= 0.f ? v.y : NEG_SLOPE * v.y,
                       v.z >= 0.f ? v.z : NEG_SLOPE * v.z,
                       v.w >= 0.f ? v.w : NEG_SLOPE * v.w);
}

// ---- gather: one wave per node. logits computed inline; butterfly softmax;
//      chunk-parallel alpha finalize (write-once to alphaBuf); LDS-staged message loop; gelu ----
__global__ __launch_bounds__(256) void k_gather(const int* __restrict__ ei, const int* __restrict__ et,
                                                const int* __restrict__ offs, const int* __restrict__ eidx,
                                                const float* __restrict__ h, const float* __restrict__ rel_emb,
                                                const float* __restrict__ a_src, const float* __restrict__ a_dst,
                                                const float* __restrict__ a_rel,
                                                float* __restrict__ alphaBuf, float* __restrict__ out) {
    __shared__ int   s_src[4][64];
    __shared__ int   s_t[4][64];
    __shared__ float s_al[4][64][4];
    int wid = threadIdx.x >> 6;
    int lane = threadIdx.x & 63;
    int n = blockIdx.x * 4 + wid;
    if (n >= N_NODES) return;
    int start = offs[n], end = offs[n + 1];
    int deg = end - start;
    int hd = lane >> 4;
    int c = lane * 2;
    float4 ad4 = *reinterpret_cast<const float4*>(a_dst + (long)n * H);   // wave-uniform

    // ---- phase A: logits (chunk 0 kept in regs) + max butterfly ----
    float4 lg0 = make_float4(NEG_BIG, NEG_BIG, NEG_BIG, NEG_BIG);
    int eid0 = 0, src0 = 0, t0 = 0;
    if (lane < deg) {
        eid0 = eidx[start + lane];
        src0 = ei[eid0];
        t0   = et[eid0];
        float4 ls = *reinterpret_cast<const float4*>(a_src + (long)src0 * H);
        float4 lr = *reinterpret_cast<const float4*>(a_rel + (long)t0 * H);
        lg0 = lrelu4(add4(add4(ls, ad4), lr));
    }
    float4 m4 = lg0;
    for (int base = start + 64; base < end; base += 64) {
        if (base + lane < end) {
            int eid = eidx[base + lane];
            float4 ls = *reinterpret_cast<const float4*>(a_src + (long)ei[eid] * H);
            float4 lr = *reinterpret_cast<const float4*>(a_rel + (long)et[eid] * H);
            m4 = max4(m4, lrelu4(add4(add4(ls, ad4), lr)));
        }
    }
    #pragma unroll
    for (int off = 32; off >= 1; off >>= 1) {
        float4 o = make_float4(__shfl_xor(m4.x, off), __shfl_xor(m4.y, off),
                               __shfl_xor(m4.z, off), __shfl_xor(m4.w, off));
        m4 = max4(m4, o);
    }

    // ---- phase B: exp-sum butterfly ----
    float4 e0 = make_float4(expf(lg0.x - m4.x), expf(lg0.y - m4.y),
                            expf(lg0.z - m4.z), expf(lg0.w - m4.w));  // idle lanes -> exp(-big)=0
    float4 z4 = e0;
    for (int base = start + 64; base < end; base += 64) {
        if (base + lane < end) {
            int eid = eidx[base + lane];
            float4 ls = *reinterpret_cast<const float4*>(a_src + (long)ei[eid] * H);
            float4 lr = *reinterpret_cast<const float4*>(a_rel + (long)et[eid] * H);
            float4 lg = lrelu4(add4(add4(ls, ad4), lr));
            z4 = add4(z4, make_float4(expf(lg.x - m4.x), expf(lg.y - m4.y),
                                      expf(lg.z - m4.z), expf(lg.w - m4.w)));
        }
    }
    #pragma unroll
    for (int off = 32; off >= 1; off >>= 1) {
        float4 o = make_float4(__shfl_xor(z4.x, off), __shfl_xor(z4.y, off),
                               __shfl_xor(z4.z, off), __shfl_xor(z4.w, off));
        z4 = add4(z4, o);
    }
    float4 rz4 = make_float4(1.0f / (z4.x + 1e-16f), 1.0f / (z4.y + 1e-16f),
                             1.0f / (z4.z + 1e-16f), 1.0f / (z4.w + 1e-16f));

    // ---- phase C: per-chunk alpha finalize (parallel) + LDS stage + message loop ----
    float accx = 0.f, accy = 0.f;
    for (int base = start; base < end; base += 64) {
        int cntc = end - base; if (cntc > 64) cntc = 64;
        int eid = eid0, src = src0, t = t0;
        float4 af;
        if (base == start) {
            af = make_float4(e0.x * rz4.x, e0.y * rz4.y, e0.z * rz4.z, e0.w * rz4.w);
        } else {
            af = make_float4(0, 0, 0, 0);
            if (lane < cntc) {
                eid = eidx[base + lane];
                src = ei[eid];
                t   = et[eid];
                float4 ls = *reinterpret_cast<const float4*>(a_src + (long)src * H);
                float4 lr = *reinterpret_cast<const float4*>(a_rel + (long)t * H);
                float4 lg = lrelu4(add4(add4(ls, ad4), lr));
                af = make_float4(expf(lg.x - m4.x) * rz4.x, expf(lg.y - m4.y) * rz4.y,
                                 expf(lg.z - m4.z) * rz4.z, expf(lg.w - m4.w) * rz4.w);
            }
        }
        if (lane < cntc) {
            s_src[wid][lane] = src;
            s_t[wid][lane]   = t;
            *reinterpret_cast<float4*>(&s_al[wid][lane][0]) = af;
            *reinterpret_cast<float4*>(alphaBuf + (long)eid * H) = af;   // final alpha, write-once
        }
        // wave-synchronous: same wave wrote, same wave reads (lockstep wave64)
        for (int j = 0; j < cntc; ++j) {
            int   sj = s_src[wid][j];
            int   tj = s_t[wid][j];
            float al = s_al[wid][j][hd];
            float2 hv = *reinterpret_cast<const float2*>(h + (long)sj * D + c);
            float2 rv = *reinterpret_cast<const float2*>(rel_emb + (long)tj * D + c);
            accx += (hv.x + rv.x) * al;
            accy += (hv.y + rv.y) * al;
        }
    }
    // gelu (tanh approx, jax default)
    float g0 = 0.5f * accx * (1.0f + tanhf(0.7978845608028654f * (accx + 0.044715f * accx * accx * accx)));
    float g1 = 0.5f * accy * (1.0f + tanhf(0.7978845608028654f * (accy + 0.044715f * accy * accy * accy)));
    *reinterpret_cast<float2*>(out + (long)n * D + c) = make_float2(g0, g1);
}

extern "C" void kernel_launch(void* const* d_in, const int* in_sizes, int n_in,
                              void* d_out, int out_size, void* d_ws, size_t ws_size,
                              hipStream_t stream) {
    const float* x        = (const float*)d_in[0];
    const float* W        = (const float*)d_in[1];
    const float* rel_emb  = (const float*)d_in[2];
    const float* att_src  = (const float*)d_in[3];
    const float* att_dst  = (const float*)d_in[4];
    const float* att_rel  = (const float*)d_in[5];
    const int*   ei       = (const int*)d_in[6];
    const int*   et       = (const int*)d_in[7];

    float* out      = (float*)d_out;                 // [N, D]
    float* alphaBuf = out + (long)N_NODES * D;       // [E, H] final alpha

    float*    h      = (float*)d_ws;                      // [N, D]
    float*    a_src  = h + (long)N_NODES * D;             // [N, H]
    float*    a_dst  = a_src + (long)N_NODES * H;         // [N, H]
    float*    a_rel  = a_dst + (long)N_NODES * H;         // [R, H]
    int*      cursor = (int*)(a_rel + R * H);             // [N]  (histogram, then fill cursor)
    int*      offs   = cursor + N_NODES;                  // [N+1]
    int*      blksum = offs + N_NODES + 1;                // [128]
    int*      eidx   = blksum + 128;                      // [E]

    const int NBLK = (N_NODES + 1023) / 1024;

    hipMemsetAsync(cursor, 0, N_NODES * sizeof(int), stream);
    k_hist<<<(N_EDGES + 255) / 256, 256, 0, stream>>>(ei, cursor);
    k_gemm<<<(N_NODES + 31) / 32, 256, 0, stream>>>(x, W, h);
    k_nodeatt<<<(N_NODES * H + 255) / 256, 256, 0, stream>>>(h, att_src, att_dst, a_src, a_dst);
    k_relatt<<<1, 256, 0, stream>>>(rel_emb, att_rel, a_rel);
    k_scan1<<<NBLK, 1024, 0, stream>>>(cursor, offs, blksum);
    k_scan2<<<1, 64, 0, stream>>>(blksum, NBLK);
    k_scan3<<<(N_NODES + 255) / 256, 256, 0, stream>>>(offs, blksum, cursor);
    k_fill<<<(N_EDGES + 255) / 256, 256, 0, stream>>>(ei, cursor, eidx);
    k_gather<<<(N_NODES + 3) / 4, 256, 0, stream>>>(ei, et, offs, eidx, h, rel_emb,
                                                    a_src, a_dst, a_rel, alphaBuf, out);
}

// Round 5
// 365.667 us; speedup vs baseline: 3.6091x; 1.0662x over previous
//
#include <hip/hip_runtime.h>

#define N_NODES 100000
#define N_EDGES 1000000
#define D 128
#define H 4
#define Dh 32
#define R 64
#define NEG_SLOPE 0.2f
#define NEG_BIG -3.0e38f

typedef unsigned int uint;

__device__ __forceinline__ float4 ld4(const float* p) { return *reinterpret_cast<const float4*>(p); }
__device__ __forceinline__ float4 max4(float4 a, float4 b) {
    return make_float4(fmaxf(a.x, b.x), fmaxf(a.y, b.y), fmaxf(a.z, b.z), fmaxf(a.w, b.w));
}
__device__ __forceinline__ float4 add4(float4 a, float4 b) {
    return make_float4(a.x + b.x, a.y + b.y, a.z + b.z, a.w + b.w);
}
__device__ __forceinline__ float4 lrelu4(float4 v) {
    return make_float4(v.x >= 0.f ? v.x : NEG_SLOPE * v.x,
                       v.y >= 0.f ? v.y : NEG_SLOPE * v.y,
                       v.z >= 0.f ? v.z : NEG_SLOPE * v.z,
                       v.w >= 0.f ? v.w : NEG_SLOPE * v.w);
}
__device__ __forceinline__ float bl(uint u) { return __uint_as_float(u << 16); }
__device__ __forceinline__ float bh(uint u) { return __uint_as_float(u & 0xFFFF0000u); }
__device__ __forceinline__ unsigned short f2bf(float f) {
    // round-to-nearest-even bf16
    uint u = __float_as_uint(f);
    u += 0x7FFF + ((u >> 16) & 1);
    return (unsigned short)(u >> 16);
}

// ---- histogram of dst ----
__global__ __launch_bounds__(256) void k_hist(const int* __restrict__ ei, int* __restrict__ cnt) {
    int e = blockIdx.x * 256 + threadIdx.x;
    if (e >= N_EDGES) return;
    atomicAdd(cnt + ei[N_EDGES + e], 1);
}

// ---- GEMM: h = x @ W (bf16 out) + fused a_src/a_dst epilogue ----
__global__ __launch_bounds__(256) void k_gemm(const float* __restrict__ x, const float* __restrict__ W,
                                              const float* __restrict__ att_src, const float* __restrict__ att_dst,
                                              unsigned short* __restrict__ hb,
                                              float* __restrict__ a_src, float* __restrict__ a_dst) {
    __shared__ float Wl[128 * 128];   // 64 KB
    __shared__ float Xl[32 * 128];    // 16 KB
    for (int i = threadIdx.x; i < 128 * 128 / 4; i += 256)
        reinterpret_cast<float4*>(Wl)[i] = reinterpret_cast<const float4*>(W)[i];
    const int tc = threadIdx.x & 31;   // cols tc*4..+3  (head = tc>>3)
    const int tr = threadIdx.x >> 5;   // rows tr*4..+3

    int rowBase = blockIdx.x * 32;
    for (int i = threadIdx.x; i < 32 * 128 / 4; i += 256) {
        int idx = i * 4; int r = idx >> 7; int c = idx & 127;
        int gr = rowBase + r;
        float4 v = make_float4(0, 0, 0, 0);
        if (gr < N_NODES) v = ld4(x + (long)gr * D + c);
        reinterpret_cast<float4*>(Xl)[i] = v;
    }
    __syncthreads();
    float acc[4][4] = {};
    #pragma unroll 8
    for (int k4 = 0; k4 < 32; ++k4) {
        float4 xv[4], wv[4];
        #pragma unroll
        for (int j = 0; j < 4; ++j) xv[j] = ld4(Xl + (tr * 4 + j) * 128 + k4 * 4);
        #pragma unroll
        for (int kk = 0; kk < 4; ++kk) wv[kk] = ld4(Wl + (k4 * 4 + kk) * 128 + tc * 4);
        #pragma unroll
        for (int j = 0; j < 4; ++j) {
            acc[j][0] += xv[j].x * wv[0].x + xv[j].y * wv[1].x + xv[j].z * wv[2].x + xv[j].w * wv[3].x;
            acc[j][1] += xv[j].x * wv[0].y + xv[j].y * wv[1].y + xv[j].z * wv[2].y + xv[j].w * wv[3].y;
            acc[j][2] += xv[j].x * wv[0].z + xv[j].y * wv[1].z + xv[j].z * wv[2].z + xv[j].w * wv[3].z;
            acc[j][3] += xv[j].x * wv[0].w + xv[j].y * wv[1].w + xv[j].z * wv[2].w + xv[j].w * wv[3].w;
        }
    }
    // bf16 h store
    #pragma unroll
    for (int j = 0; j < 4; ++j) {
        int gr = rowBase + tr * 4 + j;
        if (gr < N_NODES) {
            ushort4 hv = make_ushort4(f2bf(acc[j][0]), f2bf(acc[j][1]), f2bf(acc[j][2]), f2bf(acc[j][3]));
            *reinterpret_cast<ushort4*>(hb + (long)gr * D + tc * 4) = hv;
        }
    }
    // fused nodeatt: per-head dot, reduce across the 8 threads (tc groups of 8) of each head
    float4 av = reinterpret_cast<const float4*>(att_src)[tc];
    float4 dv = reinterpret_cast<const float4*>(att_dst)[tc];
    float ps[4], pd[4];
    #pragma unroll
    for (int j = 0; j < 4; ++j) {
        ps[j] = acc[j][0] * av.x + acc[j][1] * av.y + acc[j][2] * av.z + acc[j][3] * av.w;
        pd[j] = acc[j][0] * dv.x + acc[j][1] * dv.y + acc[j][2] * dv.z + acc[j][3] * dv.w;
    }
    #pragma unroll
    for (int off = 1; off <= 4; off <<= 1) {
        #pragma unroll
        for (int j = 0; j < 4; ++j) {
            ps[j] += __shfl_xor(ps[j], off);
            pd[j] += __shfl_xor(pd[j], off);
        }
    }
    if ((tc & 7) == 0) {
        int head = tc >> 3;
        #pragma unroll
        for (int j = 0; j < 4; ++j) {
            int gr = rowBase + tr * 4 + j;
            if (gr < N_NODES) {
                a_src[(long)gr * H + head] = ps[j];
                a_dst[(long)gr * H + head] = pd[j];
            }
        }
    }
}

// ---- per-relation partial a_rel[r,h] + bf16 rel_emb copy ----
__global__ __launch_bounds__(256) void k_relatt(const float* __restrict__ rel_emb,
                                                const float* __restrict__ att_rel,
                                                float* __restrict__ a_rel,
                                                unsigned short* __restrict__ relb) {
    int i = threadIdx.x;   // R*H = 256
    int t = i >> 2, hd = i & 3;
    const float* rp = rel_emb + (long)t * D + hd * Dh;
    const float* ar = att_rel + hd * Dh;
    float s = 0.f;
    #pragma unroll
    for (int j = 0; j < 8; ++j) {
        float4 rv = ld4(rp + j * 4);
        float4 av = ld4(ar + j * 4);
        s += rv.x * av.x + rv.y * av.y + rv.z * av.z + rv.w * av.w;
    }
    a_rel[i] = s;
    for (int idx = i; idx < R * D / 4; idx += 256) {
        float4 v = reinterpret_cast<const float4*>(rel_emb)[idx];
        ushort4 b = make_ushort4(f2bf(v.x), f2bf(v.y), f2bf(v.z), f2bf(v.w));
        reinterpret_cast<ushort4*>(relb)[idx] = b;
    }
}

// ---- scan stage 1 ----
__global__ __launch_bounds__(1024) void k_scan1(const int* __restrict__ cnt, int* __restrict__ offs,
                                                int* __restrict__ blksum) {
    __shared__ int s[1024];
    int tid = threadIdx.x;
    int i = blockIdx.x * 1024 + tid;
    int v = (i < N_NODES) ? cnt[i] : 0;
    s[tid] = v;
    __syncthreads();
    #pragma unroll
    for (int off = 1; off < 1024; off <<= 1) {
        int t = (tid >= off) ? s[tid - off] : 0;
        __syncthreads();
        s[tid] += t;
        __syncthreads();
    }
    if (i < N_NODES) offs[i] = s[tid] - v;
    if (tid == 1023) blksum[blockIdx.x] = s[1023];
}

__global__ void k_scan2(int* __restrict__ blksum, int nblk) {
    if (threadIdx.x == 0 && blockIdx.x == 0) {
        int run = 0;
        for (int b = 0; b < nblk; ++b) { int t = blksum[b]; blksum[b] = run; run += t; }
    }
}

__global__ __launch_bounds__(256) void k_scan3(int* __restrict__ offs, const int* __restrict__ blksum,
                                               int* __restrict__ cursor) {
    int i = blockIdx.x * 256 + threadIdx.x;
    if (i < N_NODES) {
        int o = offs[i] + blksum[i >> 10];
        offs[i] = o;
        cursor[i] = o;
        if (i == 0) offs[N_NODES] = N_EDGES;
    }
}

// ---- fill CSR edge-id list ----
__global__ __launch_bounds__(256) void k_fill(const int* __restrict__ ei, int* __restrict__ cursor,
                                              int* __restrict__ eidx) {
    int e = blockIdx.x * 256 + threadIdx.x;
    if (e >= N_EDGES) return;
    int dst = ei[N_EDGES + e];
    int pos = atomicAdd(cursor + dst, 1);
    eidx[pos] = e;
}

// ---- gather: one 16-lane group per node (16 nodes / 256-thread block) ----
__global__ __launch_bounds__(256) void k_gather(const int* __restrict__ ei, const int* __restrict__ et,
                                                const int* __restrict__ offs, const int* __restrict__ eidx,
                                                const unsigned short* __restrict__ hb,
                                                const unsigned short* __restrict__ relb,
                                                const float* __restrict__ a_src, const float* __restrict__ a_dst,
                                                const float* __restrict__ a_rel,
                                                float* __restrict__ alphaBuf, float* __restrict__ out) {
    __shared__ int   s_so[16][16];      // src byte offset (src*256)
    __shared__ int   s_to[16][16];      // rel byte offset (t*256)
    __shared__ float s_al[16][16][4];   // alpha4 per edge slot
    int tid = threadIdx.x;
    int nid = tid >> 4;     // node slot in block
    int l   = tid & 15;     // lane in group
    int n = blockIdx.x * 16 + nid;
    if (n >= N_NODES) return;
    int start = offs[n], end = offs[n + 1];
    int deg = end - start;
    float4 ad4 = ld4(a_dst + (long)n * H);

    // ---- phase A: chunk-0 logits in regs + max butterfly over 16 lanes ----
    float4 lg0 = make_float4(NEG_BIG, NEG_BIG, NEG_BIG, NEG_BIG);
    int eid0 = 0, so0 = 0, to0 = 0;
    bool act0 = l < deg;
    if (act0) {
        eid0 = eidx[start + l];
        int s = ei[eid0], t = et[eid0];
        so0 = s << 8; to0 = t << 8;
        lg0 = lrelu4(add4(add4(ld4(a_src + (long)s * H), ad4), ld4(a_rel + (long)t * H)));
    }
    float4 m4 = lg0;
    for (int base = start + 16; base < end; base += 16) {
        if (base + l < end) {
            int eid = eidx[base + l];
            int s = ei[eid], t = et[eid];
            m4 = max4(m4, lrelu4(add4(add4(ld4(a_src + (long)s * H), ad4), ld4(a_rel + (long)t * H))));
        }
    }
    #pragma unroll
    for (int off = 1; off <= 8; off <<= 1) {
        float4 o = make_float4(__shfl_xor(m4.x, off), __shfl_xor(m4.y, off),
                               __shfl_xor(m4.z, off), __shfl_xor(m4.w, off));
        m4 = max4(m4, o);
    }

    // ---- phase B: exp-sum butterfly ----
    float4 e0 = make_float4(0, 0, 0, 0);
    if (act0)
        e0 = make_float4(expf(lg0.x - m4.x), expf(lg0.y - m4.y),
                         expf(lg0.z - m4.z), expf(lg0.w - m4.w));
    float4 z4 = e0;
    for (int base = start + 16; base < end; base += 16) {
        if (base + l < end) {
            int eid = eidx[base + l];
            int s = ei[eid], t = et[eid];
            float4 lg = lrelu4(add4(add4(ld4(a_src + (long)s * H), ad4), ld4(a_rel + (long)t * H)));
            z4 = add4(z4, make_float4(expf(lg.x - m4.x), expf(lg.y - m4.y),
                                      expf(lg.z - m4.z), expf(lg.w - m4.w)));
        }
    }
    #pragma unroll
    for (int off = 1; off <= 8; off <<= 1) {
        float4 o = make_float4(__shfl_xor(z4.x, off), __shfl_xor(z4.y, off),
                               __shfl_xor(z4.z, off), __shfl_xor(z4.w, off));
        z4 = add4(z4, o);
    }
    float4 rz4 = make_float4(1.0f / (z4.x + 1e-16f), 1.0f / (z4.y + 1e-16f),
                             1.0f / (z4.z + 1e-16f), 1.0f / (z4.w + 1e-16f));

    // ---- phase C: alpha finalize + LDS stage + message loop (8 channels/lane) ----
    const int hd = l >> 2;            // head of this lane's 8 channels
    const int cb = l * 16;            // byte offset of 8 bf16 channels in a 256B row
    const char* hbase = reinterpret_cast<const char*>(hb);
    const char* rbase = reinterpret_cast<const char*>(relb);
    float acc[8] = {};
    for (int base = start; base < end; base += 16) {
        int cntc = end - base; if (cntc > 16) cntc = 16;
        int eid = eid0, so = so0, to = to0;
        float4 af;
        if (base == start) {
            af = make_float4(e0.x * rz4.x, e0.y * rz4.y, e0.z * rz4.z, e0.w * rz4.w);
        } else {
            af = make_float4(0, 0, 0, 0);
            if (l < cntc) {
                eid = eidx[base + l];
                int s = ei[eid], t = et[eid];
                so = s << 8; to = t << 8;
                float4 lg = lrelu4(add4(add4(ld4(a_src + (long)s * H), ad4), ld4(a_rel + (long)t * H)));
                af = make_float4(expf(lg.x - m4.x) * rz4.x, expf(lg.y - m4.y) * rz4.y,
                                 expf(lg.z - m4.z) * rz4.z, expf(lg.w - m4.w) * rz4.w);
            }
        }
        if (l < cntc) {
            s_so[nid][l] = so;
            s_to[nid][l] = to;
            *reinterpret_cast<float4*>(&s_al[nid][l][0]) = af;
            *reinterpret_cast<float4*>(alphaBuf + (long)eid * H) = af;   // final alpha, write-once
        }
        // wave-synchronous: writers and readers are the same wave (lockstep)
        for (int j = 0; j < cntc; ++j) {
            int soj = s_so[nid][j];
            int toj = s_to[nid][j];
            float al = s_al[nid][j][hd];
            uint4 hu = *reinterpret_cast<const uint4*>(hbase + soj + cb);
            uint4 ru = *reinterpret_cast<const uint4*>(rbase + toj + cb);
            acc[0] += (bl(hu.x) + bl(ru.x)) * al;
            acc[1] += (bh(hu.x) + bh(ru.x)) * al;
            acc[2] += (bl(hu.y) + bl(ru.y)) * al;
            acc[3] += (bh(hu.y) + bh(ru.y)) * al;
            acc[4] += (bl(hu.z) + bl(ru.z)) * al;
            acc[5] += (bh(hu.z) + bh(ru.z)) * al;
            acc[6] += (bl(hu.w) + bl(ru.w)) * al;
            acc[7] += (bh(hu.w) + bh(ru.w)) * al;
        }
    }
    // gelu (tanh approx, jax default)
    float g[8];
    #pragma unroll
    for (int k = 0; k < 8; ++k) {
        float xx = acc[k];
        g[k] = 0.5f * xx * (1.0f + tanhf(0.7978845608028654f * (xx + 0.044715f * xx * xx * xx)));
    }
    float* op = out + (long)n * D + l * 8;
    *reinterpret_cast<float4*>(op)     = make_float4(g[0], g[1], g[2], g[3]);
    *reinterpret_cast<float4*>(op + 4) = make_float4(g[4], g[5], g[6], g[7]);
}

extern "C" void kernel_launch(void* const* d_in, const int* in_sizes, int n_in,
                              void* d_out, int out_size, void* d_ws, size_t ws_size,
                              hipStream_t stream) {
    const float* x        = (const float*)d_in[0];
    const float* W        = (const float*)d_in[1];
    const float* rel_emb  = (const float*)d_in[2];
    const float* att_src  = (const float*)d_in[3];
    const float* att_dst  = (const float*)d_in[4];
    const float* att_rel  = (const float*)d_in[5];
    const int*   ei       = (const int*)d_in[6];
    const int*   et       = (const int*)d_in[7];

    float* out      = (float*)d_out;                 // [N, D]
    float* alphaBuf = out + (long)N_NODES * D;       // [E, H] final alpha

    unsigned short* hb   = (unsigned short*)d_ws;               // [N, D] bf16
    unsigned short* relb = hb + (long)N_NODES * D;              // [R, D] bf16
    float*    a_src  = (float*)(relb + (long)R * D);            // [N, H]
    float*    a_dst  = a_src + (long)N_NODES * H;               // [N, H]
    float*    a_rel  = a_dst + (long)N_NODES * H;               // [R, H]
    int*      cursor = (int*)(a_rel + R * H);                   // [N]
    int*      offs   = cursor + N_NODES;                        // [N+1]
    int*      blksum = offs + N_NODES + 1;                      // [128]
    int*      eidx   = blksum + 128;                            // [E]

    const int NBLK = (N_NODES + 1023) / 1024;

    hipMemsetAsync(cursor, 0, N_NODES * sizeof(int), stream);
    k_hist<<<(N_EDGES + 255) / 256, 256, 0, stream>>>(ei, cursor);
    k_gemm<<<(N_NODES + 31) / 32, 256, 0, stream>>>(x, W, att_src, att_dst, hb, a_src, a_dst);
    k_relatt<<<1, 256, 0, stream>>>(rel_emb, att_rel, a_rel, relb);
    k_scan1<<<NBLK, 1024, 0, stream>>>(cursor, offs, blksum);
    k_scan2<<<1, 64, 0, stream>>>(blksum, NBLK);
    k_scan3<<<(N_NODES + 255) / 256, 256, 0, stream>>>(offs, blksum, cursor);
    k_fill<<<(N_EDGES + 255) / 256, 256, 0, stream>>>(ei, cursor, eidx);
    k_gather<<<(N_NODES + 15) / 16, 256, 0, stream>>>(ei, et, offs, eidx, hb, relb,
                                                      a_src, a_dst, a_rel, alphaBuf, out);
}

// Round 6
// 280.663 us; speedup vs baseline: 4.7022x; 1.3029x over previous
//
#include <hip/hip_runtime.h>

#define N_NODES 100000
#define N_EDGES 1000000
#define D 128
#define H 4
#define Dh 32
#define R 64
#define NEG_SLOPE 0.2f
#define NEG_BIG -3.0e38f

typedef unsigned int uint;
typedef __attribute__((ext_vector_type(8))) short bf16x8;
typedef __attribute__((ext_vector_type(4))) float f32x4;

__device__ __forceinline__ float4 ld4(const float* p) { return *reinterpret_cast<const float4*>(p); }
__device__ __forceinline__ float4 max4(float4 a, float4 b) {
    return make_float4(fmaxf(a.x, b.x), fmaxf(a.y, b.y), fmaxf(a.z, b.z), fmaxf(a.w, b.w));
}
__device__ __forceinline__ float4 add4(float4 a, float4 b) {
    return make_float4(a.x + b.x, a.y + b.y, a.z + b.z, a.w + b.w);
}
__device__ __forceinline__ float4 lrelu4(float4 v) {
    return make_float4(v.x >= 0.f ? v.x : NEG_SLOPE * v.x,
                       v.y >= 0.f ? v.y : NEG_SLOPE * v.y,
                       v.z >= 0.f ? v.z : NEG_SLOPE * v.z,
                       v.w >= 0.f ? v.w : NEG_SLOPE * v.w);
}
__device__ __forceinline__ float bl(uint u) { return __uint_as_float(u << 16); }
__device__ __forceinline__ float bh(uint u) { return __uint_as_float(u & 0xFFFF0000u); }
__device__ __forceinline__ unsigned short f2bf(float f) {
    uint u = __float_as_uint(f);
    u += 0x7FFF + ((u >> 16) & 1);
    return (unsigned short)(u >> 16);
}
// permuted row layout: stored position p holds channel col(p) = (p&7)*16 + (p>>3)

// ---- histogram of dst ----
__global__ __launch_bounds__(256) void k_hist(const int* __restrict__ ei, int* __restrict__ cnt) {
    int e = blockIdx.x * 256 + threadIdx.x;
    if (e >= N_EDGES) return;
    atomicAdd(cnt + ei[N_EDGES + e], 1);
}

// ---- pack W -> Wt[col][k] bf16 ----
__global__ __launch_bounds__(256) void k_pack(const float* __restrict__ W, unsigned short* __restrict__ Wt) {
    int i = blockIdx.x * 256 + threadIdx.x;
    if (i >= D * D) return;
    int col = i >> 7, k = i & 127;
    Wt[i] = f2bf(W[(long)k * D + col]);
}

// ---- MFMA GEMM: h = x @ W, bf16, permuted-row store. No LDS. ----
__global__ __launch_bounds__(256) void k_gemm(const float* __restrict__ x,
                                              const unsigned short* __restrict__ Wt,
                                              unsigned short* __restrict__ hb) {
    const int lane = threadIdx.x & 63;
    const int q  = lane & 15;    // A-row / B-col / D-col within tile
    const int kg = lane >> 4;    // k-group
    int wid = blockIdx.x * 4 + (threadIdx.x >> 6);
    int nw = gridDim.x * 4;

    // B-fragments: Bf[kt][ct], lane holds Wt[ct*16+q][kt*32 + kg*8 .. +7]
    bf16x8 Bf[4][8];
    #pragma unroll
    for (int kt = 0; kt < 4; ++kt)
        #pragma unroll
        for (int ct = 0; ct < 8; ++ct)
            Bf[kt][ct] = *reinterpret_cast<const bf16x8*>(Wt + (ct * 16 + q) * D + kt * 32 + kg * 8);

    for (int rt = wid; rt < N_NODES / 16; rt += nw) {
        const float* xp = x + (long)(rt * 16 + q) * D + kg * 8;
        bf16x8 Af[4];
        #pragma unroll
        for (int kt = 0; kt < 4; ++kt) {
            float4 v0 = ld4(xp + kt * 32);
            float4 v1 = ld4(xp + kt * 32 + 4);
            bf16x8 a;
            a[0] = (short)f2bf(v0.x); a[1] = (short)f2bf(v0.y);
            a[2] = (short)f2bf(v0.z); a[3] = (short)f2bf(v0.w);
            a[4] = (short)f2bf(v1.x); a[5] = (short)f2bf(v1.y);
            a[6] = (short)f2bf(v1.z); a[7] = (short)f2bf(v1.w);
            Af[kt] = a;
        }
        f32x4 acc[8];
        #pragma unroll
        for (int ct = 0; ct < 8; ++ct) acc[ct] = (f32x4){0.f, 0.f, 0.f, 0.f};
        #pragma unroll
        for (int kt = 0; kt < 4; ++kt)
            #pragma unroll
            for (int ct = 0; ct < 8; ++ct)
                acc[ct] = __builtin_amdgcn_mfma_f32_16x16x32_bf16(Af[kt], Bf[kt][ct], acc[ct], 0, 0, 0);
        // D: lane holds rows kg*4+r, cols ct*16+q -> permuted store S[q*8+ct]
        #pragma unroll
        for (int r = 0; r < 4; ++r) {
            int orow = rt * 16 + kg * 4 + r;
            unsigned short t0 = f2bf(acc[0][r]), t1 = f2bf(acc[1][r]);
            unsigned short t2 = f2bf(acc[2][r]), t3 = f2bf(acc[3][r]);
            unsigned short t4 = f2bf(acc[4][r]), t5 = f2bf(acc[5][r]);
            unsigned short t6 = f2bf(acc[6][r]), t7 = f2bf(acc[7][r]);
            uint4 u;
            u.x = (uint)t0 | ((uint)t1 << 16);
            u.y = (uint)t2 | ((uint)t3 << 16);
            u.z = (uint)t4 | ((uint)t5 << 16);
            u.w = (uint)t6 | ((uint)t7 << 16);
            *reinterpret_cast<uint4*>(hb + (long)orow * D + q * 8) = u;
        }
    }
}

// ---- a_src/a_dst from bf16 permuted h: 16 lanes per node ----
__global__ __launch_bounds__(256) void k_nodeatt(const unsigned short* __restrict__ hb,
                                                 const float* __restrict__ att_src,
                                                 const float* __restrict__ att_dst,
                                                 float* __restrict__ a_src, float* __restrict__ a_dst) {
    int tid = threadIdx.x;
    int nid = tid >> 4, q = tid & 15;
    int n = blockIdx.x * 16 + nid;
    if (n >= N_NODES) return;
    uint4 hu = *reinterpret_cast<const uint4*>(hb + (long)n * D + q * 8);
    float hv[8] = { bl(hu.x), bh(hu.x), bl(hu.y), bh(hu.y), bl(hu.z), bh(hu.z), bl(hu.w), bh(hu.w) };
    float s1[4] = {}, s2[4] = {};
    #pragma unroll
    for (int ct = 0; ct < 8; ++ct) {
        int hd = ct >> 1;
        int dh = ((ct & 1) << 4) + q;      // channel within head
        s1[hd] += hv[ct] * att_src[hd * Dh + dh];
        s2[hd] += hv[ct] * att_dst[hd * Dh + dh];
    }
    #pragma unroll
    for (int off = 1; off <= 8; off <<= 1) {
        #pragma unroll
        for (int hd = 0; hd < 4; ++hd) {
            s1[hd] += __shfl_xor(s1[hd], off);
            s2[hd] += __shfl_xor(s2[hd], off);
        }
    }
    if (q == 0) {
        *reinterpret_cast<float4*>(a_src + (long)n * H) = make_float4(s1[0], s1[1], s1[2], s1[3]);
        *reinterpret_cast<float4*>(a_dst + (long)n * H) = make_float4(s2[0], s2[1], s2[2], s2[3]);
    }
}

// ---- a_rel[r,h] (f32) + permuted bf16 rel_emb copy ----
__global__ __launch_bounds__(256) void k_relatt(const float* __restrict__ rel_emb,
                                                const float* __restrict__ att_rel,
                                                float* __restrict__ a_rel,
                                                unsigned short* __restrict__ relb) {
    int i = threadIdx.x;   // R*H = 256
    int t = i >> 2, hd = i & 3;
    const float* rp = rel_emb + (long)t * D + hd * Dh;
    const float* ar = att_rel + hd * Dh;
    float s = 0.f;
    #pragma unroll
    for (int j = 0; j < 8; ++j) {
        float4 rv = ld4(rp + j * 4);
        float4 av = ld4(ar + j * 4);
        s += rv.x * av.x + rv.y * av.y + rv.z * av.z + rv.w * av.w;
    }
    a_rel[i] = s;
    for (int idx = i; idx < R * D; idx += 256) {
        int tt = idx >> 7, p = idx & 127;
        int col = ((p & 7) << 4) + (p >> 3);
        relb[idx] = f2bf(rel_emb[(long)tt * D + col]);
    }
}

// ---- scan stage 1 ----
__global__ __launch_bounds__(1024) void k_scan1(const int* __restrict__ cnt, int* __restrict__ offs,
                                                int* __restrict__ blksum) {
    __shared__ int s[1024];
    int tid = threadIdx.x;
    int i = blockIdx.x * 1024 + tid;
    int v = (i < N_NODES) ? cnt[i] : 0;
    s[tid] = v;
    __syncthreads();
    #pragma unroll
    for (int off = 1; off < 1024; off <<= 1) {
        int t = (tid >= off) ? s[tid - off] : 0;
        __syncthreads();
        s[tid] += t;
        __syncthreads();
    }
    if (i < N_NODES) offs[i] = s[tid] - v;
    if (tid == 1023) blksum[blockIdx.x] = s[1023];
}

__global__ void k_scan2(int* __restrict__ blksum, int nblk) {
    if (threadIdx.x == 0 && blockIdx.x == 0) {
        int run = 0;
        for (int b = 0; b < nblk; ++b) { int t = blksum[b]; blksum[b] = run; run += t; }
    }
}

__global__ __launch_bounds__(256) void k_scan3(int* __restrict__ offs, const int* __restrict__ blksum,
                                               int* __restrict__ cursor) {
    int i = blockIdx.x * 256 + threadIdx.x;
    if (i < N_NODES) {
        int o = offs[i] + blksum[i >> 10];
        offs[i] = o;
        cursor[i] = o;
        if (i == 0) offs[N_NODES] = N_EDGES;
    }
}

// ---- fill CSR edge-id list ----
__global__ __launch_bounds__(256) void k_fill(const int* __restrict__ ei, int* __restrict__ cursor,
                                              int* __restrict__ eidx) {
    int e = blockIdx.x * 256 + threadIdx.x;
    if (e >= N_EDGES) return;
    int dst = ei[N_EDGES + e];
    int pos = atomicAdd(cursor + dst, 1);
    eidx[pos] = e;
}

// ---- gather: one 16-lane group per node (16 nodes / 256-thread block) ----
__global__ __launch_bounds__(256) void k_gather(const int* __restrict__ ei, const int* __restrict__ et,
                                                const int* __restrict__ offs, const int* __restrict__ eidx,
                                                const unsigned short* __restrict__ hb,
                                                const unsigned short* __restrict__ relb,
                                                const float* __restrict__ a_src, const float* __restrict__ a_dst,
                                                const float* __restrict__ a_rel,
                                                float* __restrict__ alphaBuf, float* __restrict__ out) {
    __shared__ int   s_so[16][16];      // src byte offset (src*256)
    __shared__ int   s_to[16][16];      // rel byte offset (t*256)
    __shared__ float s_al[16][16][4];   // alpha4 per edge slot
    int tid = threadIdx.x;
    int nid = tid >> 4;
    int l   = tid & 15;
    int n = blockIdx.x * 16 + nid;
    if (n >= N_NODES) return;
    int start = offs[n], end = offs[n + 1];
    int deg = end - start;
    float4 ad4 = ld4(a_dst + (long)n * H);

    // ---- phase A: chunk-0 logits in regs + max butterfly over 16 lanes ----
    float4 lg0 = make_float4(NEG_BIG, NEG_BIG, NEG_BIG, NEG_BIG);
    int eid0 = 0, so0 = 0, to0 = 0;
    bool act0 = l < deg;
    if (act0) {
        eid0 = eidx[start + l];
        int s = ei[eid0], t = et[eid0];
        so0 = s << 8; to0 = t << 8;
        lg0 = lrelu4(add4(add4(ld4(a_src + (long)s * H), ad4), ld4(a_rel + (long)t * H)));
    }
    float4 m4 = lg0;
    for (int base = start + 16; base < end; base += 16) {
        if (base + l < end) {
            int eid = eidx[base + l];
            int s = ei[eid], t = et[eid];
            m4 = max4(m4, lrelu4(add4(add4(ld4(a_src + (long)s * H), ad4), ld4(a_rel + (long)t * H))));
        }
    }
    #pragma unroll
    for (int off = 1; off <= 8; off <<= 1) {
        float4 o = make_float4(__shfl_xor(m4.x, off), __shfl_xor(m4.y, off),
                               __shfl_xor(m4.z, off), __shfl_xor(m4.w, off));
        m4 = max4(m4, o);
    }

    // ---- phase B: exp-sum butterfly ----
    float4 e0 = make_float4(0, 0, 0, 0);
    if (act0)
        e0 = make_float4(expf(lg0.x - m4.x), expf(lg0.y - m4.y),
                         expf(lg0.z - m4.z), expf(lg0.w - m4.w));
    float4 z4 = e0;
    for (int base = start + 16; base < end; base += 16) {
        if (base + l < end) {
            int eid = eidx[base + l];
            int s = ei[eid], t = et[eid];
            float4 lg = lrelu4(add4(add4(ld4(a_src + (long)s * H), ad4), ld4(a_rel + (long)t * H)));
            z4 = add4(z4, make_float4(expf(lg.x - m4.x), expf(lg.y - m4.y),
                                      expf(lg.z - m4.z), expf(lg.w - m4.w)));
        }
    }
    #pragma unroll
    for (int off = 1; off <= 8; off <<= 1) {
        float4 o = make_float4(__shfl_xor(z4.x, off), __shfl_xor(z4.y, off),
                               __shfl_xor(z4.z, off), __shfl_xor(z4.w, off));
        z4 = add4(z4, o);
    }
    float4 rz4 = make_float4(1.0f / (z4.x + 1e-16f), 1.0f / (z4.y + 1e-16f),
                             1.0f / (z4.z + 1e-16f), 1.0f / (z4.w + 1e-16f));

    // ---- phase C: alpha finalize + LDS stage + message loop ----
    const int cb = l * 16;            // byte offset of this lane's 8 bf16 (permuted layout)
    const char* hbase = reinterpret_cast<const char*>(hb);
    const char* rbase = reinterpret_cast<const char*>(relb);
    float acc[8] = {};
    for (int base = start; base < end; base += 16) {
        int cntc = end - base; if (cntc > 16) cntc = 16;
        int eid = eid0, so = so0, to = to0;
        float4 af;
        if (base == start) {
            af = make_float4(e0.x * rz4.x, e0.y * rz4.y, e0.z * rz4.z, e0.w * rz4.w);
        } else {
            af = make_float4(0, 0, 0, 0);
            if (l < cntc) {
                eid = eidx[base + l];
                int s = ei[eid], t = et[eid];
                so = s << 8; to = t << 8;
                float4 lg = lrelu4(add4(add4(ld4(a_src + (long)s * H), ad4), ld4(a_rel + (long)t * H)));
                af = make_float4(expf(lg.x - m4.x) * rz4.x, expf(lg.y - m4.y) * rz4.y,
                                 expf(lg.z - m4.z) * rz4.z, expf(lg.w - m4.w) * rz4.w);
            }
        }
        if (l < cntc) {
            s_so[nid][l] = so;
            s_to[nid][l] = to;
            *reinterpret_cast<float4*>(&s_al[nid][l][0]) = af;
            *reinterpret_cast<float4*>(alphaBuf + (long)eid * H) = af;   // final alpha, write-once
        }
        // wave-synchronous: writers and readers are the same wave (lockstep)
        for (int j = 0; j < cntc; ++j) {
            int soj = s_so[nid][j];
            int toj = s_to[nid][j];
            float4 alj = *reinterpret_cast<float4*>(&s_al[nid][j][0]);
            uint4 hu = *reinterpret_cast<const uint4*>(hbase + soj + cb);
            uint4 ru = *reinterpret_cast<const uint4*>(rbase + toj + cb);
            acc[0] += (bl(hu.x) + bl(ru.x)) * alj.x;
            acc[1] += (bh(hu.x) + bh(ru.x)) * alj.x;
            acc[2] += (bl(hu.y) + bl(ru.y)) * alj.y;
            acc[3] += (bh(hu.y) + bh(ru.y)) * alj.y;
            acc[4] += (bl(hu.z) + bl(ru.z)) * alj.z;
            acc[5] += (bh(hu.z) + bh(ru.z)) * alj.z;
            acc[6] += (bl(hu.w) + bl(ru.w)) * alj.w;
            acc[7] += (bh(hu.w) + bh(ru.w)) * alj.w;
        }
    }
    // gelu (tanh approx) + de-permuted store: acc[i] is channel i*16 + l
    #pragma unroll
    for (int i = 0; i < 8; ++i) {
        float xx = acc[i];
        float g = 0.5f * xx * (1.0f + tanhf(0.7978845608028654f * (xx + 0.044715f * xx * xx * xx)));
        out[(long)n * D + i * 16 + l] = g;
    }
}

extern "C" void kernel_launch(void* const* d_in, const int* in_sizes, int n_in,
                              void* d_out, int out_size, void* d_ws, size_t ws_size,
                              hipStream_t stream) {
    const float* x        = (const float*)d_in[0];
    const float* W        = (const float*)d_in[1];
    const float* rel_emb  = (const float*)d_in[2];
    const float* att_src  = (const float*)d_in[3];
    const float* att_dst  = (const float*)d_in[4];
    const float* att_rel  = (const float*)d_in[5];
    const int*   ei       = (const int*)d_in[6];
    const int*   et       = (const int*)d_in[7];

    float* out      = (float*)d_out;                 // [N, D]
    float* alphaBuf = out + (long)N_NODES * D;       // [E, H] final alpha

    unsigned short* hb   = (unsigned short*)d_ws;               // [N, D] bf16 (permuted rows)
    unsigned short* relb = hb + (long)N_NODES * D;              // [R, D] bf16 (permuted rows)
    unsigned short* Wt   = relb + (long)R * D;                  // [D, D] bf16 (transposed)
    float*    a_src  = (float*)(Wt + (long)D * D);              // [N, H]
    float*    a_dst  = a_src + (long)N_NODES * H;               // [N, H]
    float*    a_rel  = a_dst + (long)N_NODES * H;               // [R, H]
    int*      cursor = (int*)(a_rel + R * H);                   // [N]
    int*      offs   = cursor + N_NODES;                        // [N+1]
    int*      blksum = offs + N_NODES + 1;                      // [128]
    int*      eidx   = blksum + 128;                            // [E]

    const int NBLK = (N_NODES + 1023) / 1024;

    hipMemsetAsync(cursor, 0, N_NODES * sizeof(int), stream);
    k_hist<<<(N_EDGES + 255) / 256, 256, 0, stream>>>(ei, cursor);
    k_pack<<<(D * D + 255) / 256, 256, 0, stream>>>(W, Wt);
    k_gemm<<<512, 256, 0, stream>>>(x, Wt, hb);
    k_relatt<<<1, 256, 0, stream>>>(rel_emb, att_rel, a_rel, relb);
    k_nodeatt<<<(N_NODES + 15) / 16, 256, 0, stream>>>(hb, att_src, att_dst, a_src, a_dst);
    k_scan1<<<NBLK, 1024, 0, stream>>>(cursor, offs, blksum);
    k_scan2<<<1, 64, 0, stream>>>(blksum, NBLK);
    k_scan3<<<(N_NODES + 255) / 256, 256, 0, stream>>>(offs, blksum, cursor);
    k_fill<<<(N_EDGES + 255) / 256, 256, 0, stream>>>(ei, cursor, eidx);
    k_gather<<<(N_NODES + 15) / 16, 256, 0, stream>>>(ei, et, offs, eidx, hb, relb,
                                                      a_src, a_dst, a_rel, alphaBuf, out);
}

// Round 7
// 257.556 us; speedup vs baseline: 5.1241x; 1.0897x over previous
//
#include <hip/hip_runtime.h>

#define N_NODES 100000
#define N_EDGES 1000000
#define D 128
#define H 4
#define Dh 32
#define R 64
#define NEG_SLOPE 0.2f
#define NEG_BIG -3.0e38f

typedef unsigned int uint;
typedef __attribute__((ext_vector_type(8))) short bf16x8;
typedef __attribute__((ext_vector_type(4))) float f32x4;

__device__ __forceinline__ float4 ld4(const float* p) { return *reinterpret_cast<const float4*>(p); }
__device__ __forceinline__ float4 max4(float4 a, float4 b) {
    return make_float4(fmaxf(a.x, b.x), fmaxf(a.y, b.y), fmaxf(a.z, b.z), fmaxf(a.w, b.w));
}
__device__ __forceinline__ float4 add4(float4 a, float4 b) {
    return make_float4(a.x + b.x, a.y + b.y, a.z + b.z, a.w + b.w);
}
__device__ __forceinline__ float4 lrelu4(float4 v) {
    return make_float4(v.x >= 0.f ? v.x : NEG_SLOPE * v.x,
                       v.y >= 0.f ? v.y : NEG_SLOPE * v.y,
                       v.z >= 0.f ? v.z : NEG_SLOPE * v.z,
                       v.w >= 0.f ? v.w : NEG_SLOPE * v.w);
}
__device__ __forceinline__ float4 exp4(float4 v, float4 m) {
    return make_float4(expf(v.x - m.x), expf(v.y - m.y), expf(v.z - m.z), expf(v.w - m.w));
}
__device__ __forceinline__ float bl(uint u) { return __uint_as_float(u << 16); }
__device__ __forceinline__ float bh(uint u) { return __uint_as_float(u & 0xFFFF0000u); }
__device__ __forceinline__ unsigned short f2bf(float f) {
    uint u = __float_as_uint(f);
    u += 0x7FFF + ((u >> 16) & 1);
    return (unsigned short)(u >> 16);
}
// permuted row layout: stored position p holds channel col(p) = (p&7)*16 + (p>>3)

// ---- histogram of dst ----
__global__ __launch_bounds__(256) void k_hist(const int* __restrict__ ei, int* __restrict__ cnt) {
    int e = blockIdx.x * 256 + threadIdx.x;
    if (e >= N_EDGES) return;
    atomicAdd(cnt + ei[N_EDGES + e], 1);
}

// ---- pack W -> Wt[col][k] bf16 ----
__global__ __launch_bounds__(256) void k_pack(const float* __restrict__ W, unsigned short* __restrict__ Wt) {
    int i = blockIdx.x * 256 + threadIdx.x;
    if (i >= D * D) return;
    int col = i >> 7, k = i & 127;
    Wt[i] = f2bf(W[(long)k * D + col]);
}

// ---- MFMA GEMM: h = x @ W, bf16 permuted-row store, fused a_src/a_dst epilogue ----
__global__ __launch_bounds__(256) void k_gemm(const float* __restrict__ x,
                                              const unsigned short* __restrict__ Wt,
                                              const float* __restrict__ att_src,
                                              const float* __restrict__ att_dst,
                                              unsigned short* __restrict__ hb,
                                              float* __restrict__ a_src, float* __restrict__ a_dst) {
    const int lane = threadIdx.x & 63;
    const int q  = lane & 15;    // A-row / B-col / D-col within tile
    const int kg = lane >> 4;    // k-group
    int wid = blockIdx.x * 4 + (threadIdx.x >> 6);
    int nw = gridDim.x * 4;

    // B-fragments: Bf[kt][ct], lane holds Wt[ct*16+q][kt*32 + kg*8 .. +7]
    bf16x8 Bf[4][8];
    #pragma unroll
    for (int kt = 0; kt < 4; ++kt)
        #pragma unroll
        for (int ct = 0; ct < 8; ++ct)
            Bf[kt][ct] = *reinterpret_cast<const bf16x8*>(Wt + (ct * 16 + q) * D + kt * 32 + kg * 8);

    for (int rt = wid; rt < N_NODES / 16; rt += nw) {
        const float* xp = x + (long)(rt * 16 + q) * D + kg * 8;
        bf16x8 Af[4];
        #pragma unroll
        for (int kt = 0; kt < 4; ++kt) {
            float4 v0 = ld4(xp + kt * 32);
            float4 v1 = ld4(xp + kt * 32 + 4);
            bf16x8 a;
            a[0] = (short)f2bf(v0.x); a[1] = (short)f2bf(v0.y);
            a[2] = (short)f2bf(v0.z); a[3] = (short)f2bf(v0.w);
            a[4] = (short)f2bf(v1.x); a[5] = (short)f2bf(v1.y);
            a[6] = (short)f2bf(v1.z); a[7] = (short)f2bf(v1.w);
            Af[kt] = a;
        }
        f32x4 acc[8];
        #pragma unroll
        for (int ct = 0; ct < 8; ++ct) acc[ct] = (f32x4){0.f, 0.f, 0.f, 0.f};
        #pragma unroll
        for (int kt = 0; kt < 4; ++kt)
            #pragma unroll
            for (int ct = 0; ct < 8; ++ct)
                acc[ct] = __builtin_amdgcn_mfma_f32_16x16x32_bf16(Af[kt], Bf[kt][ct], acc[ct], 0, 0, 0);
        // D: lane holds rows kg*4+r, cols ct*16+q -> permuted store S[q*8+ct]
        #pragma unroll
        for (int r = 0; r < 4; ++r) {
            int orow = rt * 16 + kg * 4 + r;
            unsigned short t0 = f2bf(acc[0][r]), t1 = f2bf(acc[1][r]);
            unsigned short t2 = f2bf(acc[2][r]), t3 = f2bf(acc[3][r]);
            unsigned short t4 = f2bf(acc[4][r]), t5 = f2bf(acc[5][r]);
            unsigned short t6 = f2bf(acc[6][r]), t7 = f2bf(acc[7][r]);
            uint4 u;
            u.x = (uint)t0 | ((uint)t1 << 16);
            u.y = (uint)t2 | ((uint)t3 << 16);
            u.z = (uint)t4 | ((uint)t5 << 16);
            u.w = (uint)t6 | ((uint)t7 << 16);
            *reinterpret_cast<uint4*>(hb + (long)orow * D + q * 8) = u;
        }
        // fused nodeatt epilogue: a_src/a_dst from f32 accumulators
        float ps[4][4], pd[4][4];   // [r][head]
        #pragma unroll
        for (int r = 0; r < 4; ++r)
            #pragma unroll
            for (int hd = 0; hd < 4; ++hd) { ps[r][hd] = 0.f; pd[r][hd] = 0.f; }
        #pragma unroll
        for (int ct = 0; ct < 8; ++ct) {
            float av = att_src[ct * 16 + q];
            float dv = att_dst[ct * 16 + q];
            #pragma unroll
            for (int r = 0; r < 4; ++r) {
                ps[r][ct >> 1] += acc[ct][r] * av;
                pd[r][ct >> 1] += acc[ct][r] * dv;
            }
        }
        #pragma unroll
        for (int off = 1; off <= 8; off <<= 1) {
            #pragma unroll
            for (int r = 0; r < 4; ++r)
                #pragma unroll
                for (int hd = 0; hd < 4; ++hd) {
                    ps[r][hd] += __shfl_xor(ps[r][hd], off);
                    pd[r][hd] += __shfl_xor(pd[r][hd], off);
                }
        }
        if (q == 0) {
            #pragma unroll
            for (int r = 0; r < 4; ++r) {
                int orow = rt * 16 + kg * 4 + r;
                *reinterpret_cast<float4*>(a_src + (long)orow * H) =
                    make_float4(ps[r][0], ps[r][1], ps[r][2], ps[r][3]);
                *reinterpret_cast<float4*>(a_dst + (long)orow * H) =
                    make_float4(pd[r][0], pd[r][1], pd[r][2], pd[r][3]);
            }
        }
    }
}

// ---- a_rel[r,h] (f32) + permuted bf16 rel_emb copy ----
__global__ __launch_bounds__(256) void k_relatt(const float* __restrict__ rel_emb,
                                                const float* __restrict__ att_rel,
                                                float* __restrict__ a_rel,
                                                unsigned short* __restrict__ relb) {
    int i = threadIdx.x;   // R*H = 256
    int t = i >> 2, hd = i & 3;
    const float* rp = rel_emb + (long)t * D + hd * Dh;
    const float* ar = att_rel + hd * Dh;
    float s = 0.f;
    #pragma unroll
    for (int j = 0; j < 8; ++j) {
        float4 rv = ld4(rp + j * 4);
        float4 av = ld4(ar + j * 4);
        s += rv.x * av.x + rv.y * av.y + rv.z * av.z + rv.w * av.w;
    }
    a_rel[i] = s;
    for (int idx = i; idx < R * D; idx += 256) {
        int tt = idx >> 7, p = idx & 127;
        int col = ((p & 7) << 4) + (p >> 3);
        relb[idx] = f2bf(rel_emb[(long)tt * D + col]);
    }
}

// ---- scan stage 1 ----
__global__ __launch_bounds__(1024) void k_scan1(const int* __restrict__ cnt, int* __restrict__ offs,
                                                int* __restrict__ blksum) {
    __shared__ int s[1024];
    int tid = threadIdx.x;
    int i = blockIdx.x * 1024 + tid;
    int v = (i < N_NODES) ? cnt[i] : 0;
    s[tid] = v;
    __syncthreads();
    #pragma unroll
    for (int off = 1; off < 1024; off <<= 1) {
        int t = (tid >= off) ? s[tid - off] : 0;
        __syncthreads();
        s[tid] += t;
        __syncthreads();
    }
    if (i < N_NODES) offs[i] = s[tid] - v;
    if (tid == 1023) blksum[blockIdx.x] = s[1023];
}

__global__ void k_scan2(int* __restrict__ blksum, int nblk) {
    if (threadIdx.x == 0 && blockIdx.x == 0) {
        int run = 0;
        for (int b = 0; b < nblk; ++b) { int t = blksum[b]; blksum[b] = run; run += t; }
    }
}

__global__ __launch_bounds__(256) void k_scan3(int* __restrict__ offs, const int* __restrict__ blksum,
                                               int* __restrict__ cursor) {
    int i = blockIdx.x * 256 + threadIdx.x;
    if (i < N_NODES) {
        int o = offs[i] + blksum[i >> 10];
        offs[i] = o;
        cursor[i] = o;
        if (i == 0) offs[N_NODES] = N_EDGES;
    }
}

// ---- fill CSR: logits + src/rel offsets + edge id, all in CSR order ----
__global__ __launch_bounds__(256) void k_fillx(const int* __restrict__ ei, const int* __restrict__ et,
                                               const float* __restrict__ a_src, const float* __restrict__ a_dst,
                                               const float* __restrict__ a_rel,
                                               int* __restrict__ cursor,
                                               float4* __restrict__ lgCSR, int2* __restrict__ soto,
                                               int* __restrict__ eidxCSR) {
    int e = blockIdx.x * 256 + threadIdx.x;
    if (e >= N_EDGES) return;
    int src = ei[e], dst = ei[N_EDGES + e], t = et[e];
    float4 lg = lrelu4(add4(add4(ld4(a_src + (long)src * H), ld4(a_dst + (long)dst * H)),
                            ld4(a_rel + (long)t * H)));
    int pos = atomicAdd(cursor + dst, 1);
    lgCSR[pos] = lg;
    soto[pos] = make_int2(src << 8, t << 8);
    eidxCSR[pos] = e;
}

// ---- gather: one 16-lane group per node; CSR-contiguous streams; unrolled message loop ----
__global__ __launch_bounds__(256) void k_gather(const float4* __restrict__ lgCSR,
                                                const int2* __restrict__ soto,
                                                const int* __restrict__ eidxCSR,
                                                const int* __restrict__ offs,
                                                const unsigned short* __restrict__ hb,
                                                const unsigned short* __restrict__ relb,
                                                float* __restrict__ alphaBuf, float* __restrict__ out) {
    __shared__ int   s_so[16][16];
    __shared__ int   s_to[16][16];
    __shared__ float s_al[16][16][4];
    int tid = threadIdx.x;
    int nid = tid >> 4;
    int l   = tid & 15;
    int n = blockIdx.x * 16 + nid;
    if (n >= N_NODES) return;
    int start = offs[n], end = offs[n + 1];
    int deg = end - start;

    // ---- phase A: chunk-0 logits in regs + max butterfly ----
    float4 lg0 = make_float4(NEG_BIG, NEG_BIG, NEG_BIG, NEG_BIG);
    bool act0 = l < deg;
    if (act0) lg0 = lgCSR[start + l];
    float4 m4 = lg0;
    for (int base = start + 16; base < end; base += 16)
        if (base + l < end) m4 = max4(m4, lgCSR[base + l]);
    #pragma unroll
    for (int off = 1; off <= 8; off <<= 1) {
        float4 o = make_float4(__shfl_xor(m4.x, off), __shfl_xor(m4.y, off),
                               __shfl_xor(m4.z, off), __shfl_xor(m4.w, off));
        m4 = max4(m4, o);
    }

    // ---- phase B: exp-sum butterfly (chunk 0 from regs) ----
    float4 e0 = make_float4(0, 0, 0, 0);
    if (act0) e0 = exp4(lg0, m4);
    float4 z4 = e0;
    for (int base = start + 16; base < end; base += 16)
        if (base + l < end) z4 = add4(z4, exp4(lgCSR[base + l], m4));
    #pragma unroll
    for (int off = 1; off <= 8; off <<= 1) {
        float4 o = make_float4(__shfl_xor(z4.x, off), __shfl_xor(z4.y, off),
                               __shfl_xor(z4.z, off), __shfl_xor(z4.w, off));
        z4 = add4(z4, o);
    }
    float4 rz4 = make_float4(1.0f / (z4.x + 1e-16f), 1.0f / (z4.y + 1e-16f),
                             1.0f / (z4.z + 1e-16f), 1.0f / (z4.w + 1e-16f));

    // ---- phase C: alpha finalize + LDS stage + unrolled message loop ----
    const int cb = l * 16;            // byte offset of this lane's 8 bf16 (permuted layout)
    const char* hbase = reinterpret_cast<const char*>(hb);
    const char* rbase = reinterpret_cast<const char*>(relb);
    float acc[8] = {};
    for (int base = start; base < end; base += 16) {
        int cntc = end - base; if (cntc > 16) cntc = 16;
        if (l < cntc) {
            int2 st = soto[base + l];
            int eid = eidxCSR[base + l];
            float4 ex = (base == start) ? e0 : exp4(lgCSR[base + l], m4);
            float4 af = make_float4(ex.x * rz4.x, ex.y * rz4.y, ex.z * rz4.z, ex.w * rz4.w);
            s_so[nid][l] = st.x;
            s_to[nid][l] = st.y;
            *reinterpret_cast<float4*>(&s_al[nid][l][0]) = af;
            *reinterpret_cast<float4*>(alphaBuf + (long)eid * H) = af;   // final alpha, write-once
        }
        // wave-synchronous: writers and readers are the same wave (lockstep)
        int j = 0;
        for (; j + 4 <= cntc; j += 4) {
            uint4 hu[4], ru[4];
            float4 aj[4];
            #pragma unroll
            for (int u = 0; u < 4; ++u) {
                int soj = s_so[nid][j + u];
                int toj = s_to[nid][j + u];
                aj[u] = *reinterpret_cast<float4*>(&s_al[nid][j + u][0]);
                hu[u] = *reinterpret_cast<const uint4*>(hbase + soj + cb);
                ru[u] = *reinterpret_cast<const uint4*>(rbase + toj + cb);
            }
            #pragma unroll
            for (int u = 0; u < 4; ++u) {
                acc[0] += (bl(hu[u].x) + bl(ru[u].x)) * aj[u].x;
                acc[1] += (bh(hu[u].x) + bh(ru[u].x)) * aj[u].x;
                acc[2] += (bl(hu[u].y) + bl(ru[u].y)) * aj[u].y;
                acc[3] += (bh(hu[u].y) + bh(ru[u].y)) * aj[u].y;
                acc[4] += (bl(hu[u].z) + bl(ru[u].z)) * aj[u].z;
                acc[5] += (bh(hu[u].z) + bh(ru[u].z)) * aj[u].z;
                acc[6] += (bl(hu[u].w) + bl(ru[u].w)) * aj[u].w;
                acc[7] += (bh(hu[u].w) + bh(ru[u].w)) * aj[u].w;
            }
        }
        for (; j < cntc; ++j) {
            int soj = s_so[nid][j];
            int toj = s_to[nid][j];
            float4 alj = *reinterpret_cast<float4*>(&s_al[nid][j][0]);
            uint4 hu = *reinterpret_cast<const uint4*>(hbase + soj + cb);
            uint4 ru = *reinterpret_cast<const uint4*>(rbase + toj + cb);
            acc[0] += (bl(hu.x) + bl(ru.x)) * alj.x;
            acc[1] += (bh(hu.x) + bh(ru.x)) * alj.x;
            acc[2] += (bl(hu.y) + bl(ru.y)) * alj.y;
            acc[3] += (bh(hu.y) + bh(ru.y)) * alj.y;
            acc[4] += (bl(hu.z) + bl(ru.z)) * alj.z;
            acc[5] += (bh(hu.z) + bh(ru.z)) * alj.z;
            acc[6] += (bl(hu.w) + bl(ru.w)) * alj.w;
            acc[7] += (bh(hu.w) + bh(ru.w)) * alj.w;
        }
    }
    // gelu (tanh approx) + de-permuted store: acc[i] is channel i*16 + l
    #pragma unroll
    for (int i = 0; i < 8; ++i) {
        float xx = acc[i];
        float g = 0.5f * xx * (1.0f + tanhf(0.7978845608028654f * (xx + 0.044715f * xx * xx * xx)));
        out[(long)n * D + i * 16 + l] = g;
    }
}

extern "C" void kernel_launch(void* const* d_in, const int* in_sizes, int n_in,
                              void* d_out, int out_size, void* d_ws, size_t ws_size,
                              hipStream_t stream) {
    const float* x        = (const float*)d_in[0];
    const float* W        = (const float*)d_in[1];
    const float* rel_emb  = (const float*)d_in[2];
    const float* att_src  = (const float*)d_in[3];
    const float* att_dst  = (const float*)d_in[4];
    const float* att_rel  = (const float*)d_in[5];
    const int*   ei       = (const int*)d_in[6];
    const int*   et       = (const int*)d_in[7];

    float* out      = (float*)d_out;                 // [N, D]
    float* alphaBuf = out + (long)N_NODES * D;       // [E, H] final alpha

    unsigned short* hb   = (unsigned short*)d_ws;               // [N, D] bf16 (permuted rows)
    unsigned short* relb = hb + (long)N_NODES * D;              // [R, D] bf16 (permuted rows)
    unsigned short* Wt   = relb + (long)R * D;                  // [D, D] bf16 (transposed)
    float4*   lgCSR  = (float4*)(Wt + (long)D * D);             // [E] logits in CSR order
    int2*     soto   = (int2*)(lgCSR + N_EDGES);                // [E] {src*256, t*256}
    int*      eidxCSR= (int*)(soto + N_EDGES);                  // [E]
    float*    a_src  = (float*)(eidxCSR + N_EDGES);             // [N, H]
    float*    a_dst  = a_src + (long)N_NODES * H;               // [N, H]
    float*    a_rel  = a_dst + (long)N_NODES * H;               // [R, H]
    int*      cursor = (int*)(a_rel + R * H);                   // [N]
    int*      offs   = cursor + N_NODES;                        // [N+1]
    int*      blksum = offs + N_NODES + 1;                      // [128]

    const int NBLK = (N_NODES + 1023) / 1024;

    hipMemsetAsync(cursor, 0, N_NODES * sizeof(int), stream);
    k_hist<<<(N_EDGES + 255) / 256, 256, 0, stream>>>(ei, cursor);
    k_pack<<<(D * D + 255) / 256, 256, 0, stream>>>(W, Wt);
    k_gemm<<<1563, 256, 0, stream>>>(x, Wt, att_src, att_dst, hb, a_src, a_dst);
    k_relatt<<<1, 256, 0, stream>>>(rel_emb, att_rel, a_rel, relb);
    k_scan1<<<NBLK, 1024, 0, stream>>>(cursor, offs, blksum);
    k_scan2<<<1, 64, 0, stream>>>(blksum, NBLK);
    k_scan3<<<(N_NODES + 255) / 256, 256, 0, stream>>>(offs, blksum, cursor);
    k_fillx<<<(N_EDGES + 255) / 256, 256, 0, stream>>>(ei, et, a_src, a_dst, a_rel,
                                                       cursor, lgCSR, soto, eidxCSR);
    k_gather<<<(N_NODES + 15) / 16, 256, 0, stream>>>(lgCSR, soto, eidxCSR, offs,
                                                      hb, relb, alphaBuf, out);
}

// Round 8
// 241.267 us; speedup vs baseline: 5.4700x; 1.0675x over previous
//
#include <hip/hip_runtime.h>

#define N_NODES 100000
#define N_EDGES 1000000
#define D 128
#define H 4
#define Dh 32
#define R 64
#define NEG_SLOPE 0.2f
#define NEG_BIG -3.0e38f

typedef unsigned int uint;
typedef __attribute__((ext_vector_type(8))) short bf16x8;
typedef __attribute__((ext_vector_type(4))) float f32x4;

__device__ __forceinline__ float4 ld4(const float* p) { return *reinterpret_cast<const float4*>(p); }
__device__ __forceinline__ float4 max4(float4 a, float4 b) {
    return make_float4(fmaxf(a.x, b.x), fmaxf(a.y, b.y), fmaxf(a.z, b.z), fmaxf(a.w, b.w));
}
__device__ __forceinline__ float4 add4(float4 a, float4 b) {
    return make_float4(a.x + b.x, a.y + b.y, a.z + b.z, a.w + b.w);
}
__device__ __forceinline__ float4 lrelu4(float4 v) {
    return make_float4(v.x >= 0.f ? v.x : NEG_SLOPE * v.x,
                       v.y >= 0.f ? v.y : NEG_SLOPE * v.y,
                       v.z >= 0.f ? v.z : NEG_SLOPE * v.z,
                       v.w >= 0.f ? v.w : NEG_SLOPE * v.w);
}
__device__ __forceinline__ float4 exp4(float4 v, float4 m) {
    return make_float4(expf(v.x - m.x), expf(v.y - m.y), expf(v.z - m.z), expf(v.w - m.w));
}
__device__ __forceinline__ float bl(uint u) { return __uint_as_float(u << 16); }
__device__ __forceinline__ float bh(uint u) { return __uint_as_float(u & 0xFFFF0000u); }
__device__ __forceinline__ unsigned short f2bf(float f) {
    uint u = __float_as_uint(f);
    u += 0x7FFF + ((u >> 16) & 1);
    return (unsigned short)(u >> 16);
}
// permuted row layout: stored position p holds channel col(p) = (p&7)*16 + (p>>3)

// ---- histogram of dst (2 edges/thread for MLP) ----
__global__ __launch_bounds__(256) void k_hist(const int* __restrict__ ei, int* __restrict__ cnt) {
    int e = (blockIdx.x * 256 + threadIdx.x) * 2;
    if (e >= N_EDGES) return;
    int d0 = ei[N_EDGES + e];
    int d1 = (e + 1 < N_EDGES) ? ei[N_EDGES + e + 1] : -1;
    atomicAdd(cnt + d0, 1);
    if (d1 >= 0) atomicAdd(cnt + d1, 1);
}

// ---- pack W -> Wt[col][k] bf16 ----
__global__ __launch_bounds__(256) void k_pack(const float* __restrict__ W, unsigned short* __restrict__ Wt) {
    int i = blockIdx.x * 256 + threadIdx.x;
    if (i >= D * D) return;
    int col = i >> 7, k = i & 127;
    Wt[i] = f2bf(W[(long)k * D + col]);
}

// ---- MFMA GEMM: h = x @ W, bf16 permuted-row store, fused a_src/a_dst epilogue ----
__global__ __launch_bounds__(256) void k_gemm(const float* __restrict__ x,
                                              const unsigned short* __restrict__ Wt,
                                              const float* __restrict__ att_src,
                                              const float* __restrict__ att_dst,
                                              unsigned short* __restrict__ hb,
                                              float* __restrict__ a_src, float* __restrict__ a_dst) {
    const int lane = threadIdx.x & 63;
    const int q  = lane & 15;    // A-row / B-col / D-col within tile
    const int kg = lane >> 4;    // k-group
    int wid = blockIdx.x * 4 + (threadIdx.x >> 6);
    int nw = gridDim.x * 4;

    bf16x8 Bf[4][8];
    #pragma unroll
    for (int kt = 0; kt < 4; ++kt)
        #pragma unroll
        for (int ct = 0; ct < 8; ++ct)
            Bf[kt][ct] = *reinterpret_cast<const bf16x8*>(Wt + (ct * 16 + q) * D + kt * 32 + kg * 8);

    for (int rt = wid; rt < N_NODES / 16; rt += nw) {
        const float* xp = x + (long)(rt * 16 + q) * D + kg * 8;
        bf16x8 Af[4];
        #pragma unroll
        for (int kt = 0; kt < 4; ++kt) {
            float4 v0 = ld4(xp + kt * 32);
            float4 v1 = ld4(xp + kt * 32 + 4);
            bf16x8 a;
            a[0] = (short)f2bf(v0.x); a[1] = (short)f2bf(v0.y);
            a[2] = (short)f2bf(v0.z); a[3] = (short)f2bf(v0.w);
            a[4] = (short)f2bf(v1.x); a[5] = (short)f2bf(v1.y);
            a[6] = (short)f2bf(v1.z); a[7] = (short)f2bf(v1.w);
            Af[kt] = a;
        }
        f32x4 acc[8];
        #pragma unroll
        for (int ct = 0; ct < 8; ++ct) acc[ct] = (f32x4){0.f, 0.f, 0.f, 0.f};
        #pragma unroll
        for (int kt = 0; kt < 4; ++kt)
            #pragma unroll
            for (int ct = 0; ct < 8; ++ct)
                acc[ct] = __builtin_amdgcn_mfma_f32_16x16x32_bf16(Af[kt], Bf[kt][ct], acc[ct], 0, 0, 0);
        #pragma unroll
        for (int r = 0; r < 4; ++r) {
            int orow = rt * 16 + kg * 4 + r;
            unsigned short t0 = f2bf(acc[0][r]), t1 = f2bf(acc[1][r]);
            unsigned short t2 = f2bf(acc[2][r]), t3 = f2bf(acc[3][r]);
            unsigned short t4 = f2bf(acc[4][r]), t5 = f2bf(acc[5][r]);
            unsigned short t6 = f2bf(acc[6][r]), t7 = f2bf(acc[7][r]);
            uint4 u;
            u.x = (uint)t0 | ((uint)t1 << 16);
            u.y = (uint)t2 | ((uint)t3 << 16);
            u.z = (uint)t4 | ((uint)t5 << 16);
            u.w = (uint)t6 | ((uint)t7 << 16);
            *reinterpret_cast<uint4*>(hb + (long)orow * D + q * 8) = u;
        }
        // fused nodeatt epilogue
        float ps[4][4], pd[4][4];   // [r][head]
        #pragma unroll
        for (int r = 0; r < 4; ++r)
            #pragma unroll
            for (int hd = 0; hd < 4; ++hd) { ps[r][hd] = 0.f; pd[r][hd] = 0.f; }
        #pragma unroll
        for (int ct = 0; ct < 8; ++ct) {
            float av = att_src[ct * 16 + q];
            float dv = att_dst[ct * 16 + q];
            #pragma unroll
            for (int r = 0; r < 4; ++r) {
                ps[r][ct >> 1] += acc[ct][r] * av;
                pd[r][ct >> 1] += acc[ct][r] * dv;
            }
        }
        #pragma unroll
        for (int off = 1; off <= 8; off <<= 1) {
            #pragma unroll
            for (int r = 0; r < 4; ++r)
                #pragma unroll
                for (int hd = 0; hd < 4; ++hd) {
                    ps[r][hd] += __shfl_xor(ps[r][hd], off);
                    pd[r][hd] += __shfl_xor(pd[r][hd], off);
                }
        }
        if (q == 0) {
            #pragma unroll
            for (int r = 0; r < 4; ++r) {
                int orow = rt * 16 + kg * 4 + r;
                *reinterpret_cast<float4*>(a_src + (long)orow * H) =
                    make_float4(ps[r][0], ps[r][1], ps[r][2], ps[r][3]);
                *reinterpret_cast<float4*>(a_dst + (long)orow * H) =
                    make_float4(pd[r][0], pd[r][1], pd[r][2], pd[r][3]);
            }
        }
    }
}

// ---- a_rel[r,h] (f32) + permuted bf16 rel_emb copy ----
__global__ __launch_bounds__(256) void k_relatt(const float* __restrict__ rel_emb,
                                                const float* __restrict__ att_rel,
                                                float* __restrict__ a_rel,
                                                unsigned short* __restrict__ relb) {
    int i = threadIdx.x;   // R*H = 256
    int t = i >> 2, hd = i & 3;
    const float* rp = rel_emb + (long)t * D + hd * Dh;
    const float* ar = att_rel + hd * Dh;
    float s = 0.f;
    #pragma unroll
    for (int j = 0; j < 8; ++j) {
        float4 rv = ld4(rp + j * 4);
        float4 av = ld4(ar + j * 4);
        s += rv.x * av.x + rv.y * av.y + rv.z * av.z + rv.w * av.w;
    }
    a_rel[i] = s;
    for (int idx = i; idx < R * D; idx += 256) {
        int tt = idx >> 7, p = idx & 127;
        int col = ((p & 7) << 4) + (p >> 3);
        relb[idx] = f2bf(rel_emb[(long)tt * D + col]);
    }
}

// ---- scan stage 1 ----
__global__ __launch_bounds__(1024) void k_scan1(const int* __restrict__ cnt, int* __restrict__ offs,
                                                int* __restrict__ blksum) {
    __shared__ int s[1024];
    int tid = threadIdx.x;
    int i = blockIdx.x * 1024 + tid;
    int v = (i < N_NODES) ? cnt[i] : 0;
    s[tid] = v;
    __syncthreads();
    #pragma unroll
    for (int off = 1; off < 1024; off <<= 1) {
        int t = (tid >= off) ? s[tid - off] : 0;
        __syncthreads();
        s[tid] += t;
        __syncthreads();
    }
    if (i < N_NODES) offs[i] = s[tid] - v;
    if (tid == 1023) blksum[blockIdx.x] = s[1023];
}

__global__ void k_scan2(int* __restrict__ blksum, int nblk) {
    if (threadIdx.x == 0 && blockIdx.x == 0) {
        int run = 0;
        for (int b = 0; b < nblk; ++b) { int t = blksum[b]; blksum[b] = run; run += t; }
    }
}

__global__ __launch_bounds__(256) void k_scan3(int* __restrict__ offs, const int* __restrict__ blksum,
                                               int* __restrict__ cursor) {
    int i = blockIdx.x * 256 + threadIdx.x;
    if (i < N_NODES) {
        int o = offs[i] + blksum[i >> 10];
        offs[i] = o;
        cursor[i] = o;
        if (i == 0) offs[N_NODES] = N_EDGES;
    }
}

// ---- fill CSR: packed 32B record {lg(16B) | so,to,eid,pad(16B)}, 2 edges/thread ----
__global__ __launch_bounds__(256) void k_fillx(const int* __restrict__ ei, const int* __restrict__ et,
                                               const float* __restrict__ a_src, const float* __restrict__ a_dst,
                                               const float* __restrict__ a_rel,
                                               int* __restrict__ cursor,
                                               uint4* __restrict__ rec) {
    int e = (blockIdx.x * 256 + threadIdx.x) * 2;
    if (e >= N_EDGES) return;
    #pragma unroll
    for (int u = 0; u < 2; ++u) {
        int ee = e + u;
        if (ee >= N_EDGES) break;
        int src = ei[ee], dst = ei[N_EDGES + ee], t = et[ee];
        float4 lg = lrelu4(add4(add4(ld4(a_src + (long)src * H), ld4(a_dst + (long)dst * H)),
                                ld4(a_rel + (long)t * H)));
        int pos = atomicAdd(cursor + dst, 1);
        rec[(long)pos * 2]     = make_uint4(__float_as_uint(lg.x), __float_as_uint(lg.y),
                                            __float_as_uint(lg.z), __float_as_uint(lg.w));
        rec[(long)pos * 2 + 1] = make_uint4((uint)(src << 8), (uint)(t << 8), (uint)ee, 0u);
    }
}

// ---- gather: one 16-lane group per node; packed-record streams; unrolled message loop ----
__global__ __launch_bounds__(256) void k_gather(const uint4* __restrict__ rec,
                                                const int* __restrict__ offs,
                                                const unsigned short* __restrict__ hb,
                                                const unsigned short* __restrict__ relb,
                                                float* __restrict__ alphaBuf, float* __restrict__ out) {
    __shared__ int   s_so[16][16];
    __shared__ int   s_to[16][16];
    __shared__ float s_al[16][16][4];
    int tid = threadIdx.x;
    int nid = tid >> 4;
    int l   = tid & 15;
    int n = blockIdx.x * 16 + nid;
    if (n >= N_NODES) return;
    int start = offs[n], end = offs[n + 1];
    int deg = end - start;

    // ---- phase A: chunk-0 record in regs + max butterfly ----
    float4 lg0 = make_float4(NEG_BIG, NEG_BIG, NEG_BIG, NEG_BIG);
    int so0 = 0, to0 = 0, eid0 = 0;
    bool act0 = l < deg;
    if (act0) {
        uint4 r0 = rec[(long)(start + l) * 2];
        uint4 m0 = rec[(long)(start + l) * 2 + 1];
        lg0 = make_float4(__uint_as_float(r0.x), __uint_as_float(r0.y),
                          __uint_as_float(r0.z), __uint_as_float(r0.w));
        so0 = (int)m0.x; to0 = (int)m0.y; eid0 = (int)m0.z;
    }
    float4 m4 = lg0;
    for (int base = start + 16; base < end; base += 16)
        if (base + l < end) {
            uint4 r = rec[(long)(base + l) * 2];
            m4 = max4(m4, make_float4(__uint_as_float(r.x), __uint_as_float(r.y),
                                      __uint_as_float(r.z), __uint_as_float(r.w)));
        }
    #pragma unroll
    for (int off = 1; off <= 8; off <<= 1) {
        float4 o = make_float4(__shfl_xor(m4.x, off), __shfl_xor(m4.y, off),
                               __shfl_xor(m4.z, off), __shfl_xor(m4.w, off));
        m4 = max4(m4, o);
    }

    // ---- phase B: exp-sum butterfly (chunk 0 from regs) ----
    float4 e0 = make_float4(0, 0, 0, 0);
    if (act0) e0 = exp4(lg0, m4);
    float4 z4 = e0;
    for (int base = start + 16; base < end; base += 16)
        if (base + l < end) {
            uint4 r = rec[(long)(base + l) * 2];
            z4 = add4(z4, exp4(make_float4(__uint_as_float(r.x), __uint_as_float(r.y),
                                           __uint_as_float(r.z), __uint_as_float(r.w)), m4));
        }
    #pragma unroll
    for (int off = 1; off <= 8; off <<= 1) {
        float4 o = make_float4(__shfl_xor(z4.x, off), __shfl_xor(z4.y, off),
                               __shfl_xor(z4.z, off), __shfl_xor(z4.w, off));
        z4 = add4(z4, o);
    }
    float4 rz4 = make_float4(1.0f / (z4.x + 1e-16f), 1.0f / (z4.y + 1e-16f),
                             1.0f / (z4.z + 1e-16f), 1.0f / (z4.w + 1e-16f));

    // ---- phase C: alpha finalize + LDS stage + unrolled message loop ----
    const int cb = l * 16;            // byte offset of this lane's 8 bf16 (permuted layout)
    const char* hbase = reinterpret_cast<const char*>(hb);
    const char* rbase = reinterpret_cast<const char*>(relb);
    float acc[8] = {};
    for (int base = start; base < end; base += 16) {
        int cntc = end - base; if (cntc > 16) cntc = 16;
        if (l < cntc) {
            float4 ex; int so, to, eid;
            if (base == start) {
                ex = e0; so = so0; to = to0; eid = eid0;
            } else {
                uint4 r = rec[(long)(base + l) * 2];
                uint4 mt = rec[(long)(base + l) * 2 + 1];
                ex = exp4(make_float4(__uint_as_float(r.x), __uint_as_float(r.y),
                                      __uint_as_float(r.z), __uint_as_float(r.w)), m4);
                so = (int)mt.x; to = (int)mt.y; eid = (int)mt.z;
            }
            float4 af = make_float4(ex.x * rz4.x, ex.y * rz4.y, ex.z * rz4.z, ex.w * rz4.w);
            s_so[nid][l] = so;
            s_to[nid][l] = to;
            *reinterpret_cast<float4*>(&s_al[nid][l][0]) = af;
            *reinterpret_cast<float4*>(alphaBuf + (long)eid * H) = af;   // final alpha, write-once
        }
        // wave-synchronous: writers and readers are the same wave (lockstep)
        int j = 0;
        for (; j + 4 <= cntc; j += 4) {
            uint4 hu[4], ru[4];
            float4 aj[4];
            #pragma unroll
            for (int u = 0; u < 4; ++u) {
                int soj = s_so[nid][j + u];
                int toj = s_to[nid][j + u];
                aj[u] = *reinterpret_cast<float4*>(&s_al[nid][j + u][0]);
                hu[u] = *reinterpret_cast<const uint4*>(hbase + soj + cb);
                ru[u] = *reinterpret_cast<const uint4*>(rbase + toj + cb);
            }
            #pragma unroll
            for (int u = 0; u < 4; ++u) {
                acc[0] += (bl(hu[u].x) + bl(ru[u].x)) * aj[u].x;
                acc[1] += (bh(hu[u].x) + bh(ru[u].x)) * aj[u].x;
                acc[2] += (bl(hu[u].y) + bl(ru[u].y)) * aj[u].y;
                acc[3] += (bh(hu[u].y) + bh(ru[u].y)) * aj[u].y;
                acc[4] += (bl(hu[u].z) + bl(ru[u].z)) * aj[u].z;
                acc[5] += (bh(hu[u].z) + bh(ru[u].z)) * aj[u].z;
                acc[6] += (bl(hu[u].w) + bl(ru[u].w)) * aj[u].w;
                acc[7] += (bh(hu[u].w) + bh(ru[u].w)) * aj[u].w;
            }
        }
        for (; j < cntc; ++j) {
            int soj = s_so[nid][j];
            int toj = s_to[nid][j];
            float4 alj = *reinterpret_cast<float4*>(&s_al[nid][j][0]);
            uint4 hu = *reinterpret_cast<const uint4*>(hbase + soj + cb);
            uint4 ru = *reinterpret_cast<const uint4*>(rbase + toj + cb);
            acc[0] += (bl(hu.x) + bl(ru.x)) * alj.x;
            acc[1] += (bh(hu.x) + bh(ru.x)) * alj.x;
            acc[2] += (bl(hu.y) + bl(ru.y)) * alj.y;
            acc[3] += (bh(hu.y) + bh(ru.y)) * alj.y;
            acc[4] += (bl(hu.z) + bl(ru.z)) * alj.z;
            acc[5] += (bh(hu.z) + bh(ru.z)) * alj.z;
            acc[6] += (bl(hu.w) + bl(ru.w)) * alj.w;
            acc[7] += (bh(hu.w) + bh(ru.w)) * alj.w;
        }
    }
    // gelu (tanh approx) + de-permuted store: acc[i] is channel i*16 + l
    #pragma unroll
    for (int i = 0; i < 8; ++i) {
        float xx = acc[i];
        float g = 0.5f * xx * (1.0f + tanhf(0.7978845608028654f * (xx + 0.044715f * xx * xx * xx)));
        out[(long)n * D + i * 16 + l] = g;
    }
}

extern "C" void kernel_launch(void* const* d_in, const int* in_sizes, int n_in,
                              void* d_out, int out_size, void* d_ws, size_t ws_size,
                              hipStream_t stream) {
    const float* x        = (const float*)d_in[0];
    const float* W        = (const float*)d_in[1];
    const float* rel_emb  = (const float*)d_in[2];
    const float* att_src  = (const float*)d_in[3];
    const float* att_dst  = (const float*)d_in[4];
    const float* att_rel  = (const float*)d_in[5];
    const int*   ei       = (const int*)d_in[6];
    const int*   et       = (const int*)d_in[7];

    float* out      = (float*)d_out;                 // [N, D]
    float* alphaBuf = out + (long)N_NODES * D;       // [E, H] final alpha

    unsigned short* hb   = (unsigned short*)d_ws;               // [N, D] bf16 (permuted rows)
    unsigned short* relb = hb + (long)N_NODES * D;              // [R, D] bf16 (permuted rows)
    unsigned short* Wt   = relb + (long)R * D;                  // [D, D] bf16 (transposed)
    uint4*    rec    = (uint4*)(Wt + (long)D * D);              // [E*2] packed CSR records (32B/edge)
    float*    a_src  = (float*)(rec + (long)N_EDGES * 2);       // [N, H]
    float*    a_dst  = a_src + (long)N_NODES * H;               // [N, H]
    float*    a_rel  = a_dst + (long)N_NODES * H;               // [R, H]
    int*      cursor = (int*)(a_rel + R * H);                   // [N]
    int*      offs   = cursor + N_NODES;                        // [N+1]
    int*      blksum = offs + N_NODES + 1;                      // [128]

    const int NBLK = (N_NODES + 1023) / 1024;

    hipMemsetAsync(cursor, 0, N_NODES * sizeof(int), stream);
    k_hist<<<(N_EDGES / 2 + 255) / 256, 256, 0, stream>>>(ei, cursor);
    k_pack<<<(D * D + 255) / 256, 256, 0, stream>>>(W, Wt);
    k_gemm<<<1563, 256, 0, stream>>>(x, Wt, att_src, att_dst, hb, a_src, a_dst);
    k_relatt<<<1, 256, 0, stream>>>(rel_emb, att_rel, a_rel, relb);
    k_scan1<<<NBLK, 1024, 0, stream>>>(cursor, offs, blksum);
    k_scan2<<<1, 64, 0, stream>>>(blksum, NBLK);
    k_scan3<<<(N_NODES + 255) / 256, 256, 0, stream>>>(offs, blksum, cursor);
    k_fillx<<<(N_EDGES / 2 + 255) / 256, 256, 0, stream>>>(ei, et, a_src, a_dst, a_rel,
                                                           cursor, rec);
    k_gather<<<(N_NODES + 15) / 16, 256, 0, stream>>>(rec, offs, hb, relb, alphaBuf, out);
}